// Round 1
// baseline (269.567 us; speedup 1.0000x reference)
//
#include <hip/hip_runtime.h>
#include <cstddef>

#define CCH 256
#define NPIX 4096
#define NB 8
#define INVCNT (1.0f/32768.0f)
#define INVN (1.0f/4096.0f)

// ---- workspace layout (float offsets) ----
#define OFF_S      0u          // 8*256 rowsums
#define OFF_A      2048u       // A = W_w @ g_w       (256x256)
#define OFF_BM     67584u      // Bm = phi_w^T theta_w(256x256)
#define OFF_T1     133120u     // t1 = phi_w^T theta_b
#define OFF_R      133376u     // r  = theta_w^T phi_b
#define OFF_W1     133632u     // w1 = W_w @ g_b
#define OFF_C1     133888u     // c1 = phi_b . theta_b
#define OFF_G      134144u     // G  8 x 256x256
#define OFF_K      658432u     // K = A @ G  8 x 256x256
#define OFF_U      1182720u    // u = A @ s  8 x 256
#define OFF_M      1184768u    // M  8 x 256x256
#define OFF_E      1709056u    // e  8 x 256
#define OFF_ZPS    1711104u    // bn partial sums   [entry 256][c 256]
#define OFF_ZPQ    1776640u    // bn partial sumsq  [entry 256][c 256]
#define OFF_SCALE  1842176u
#define OFF_SHIFT  1842432u
#define OFF_SHARED 1842688u    // union: Gpart (8*16*65536) then Z (8*256*4096)

// ---------- generic 64x64-tile NN/TN matmul over K=256 (A,B are 256x256) ----------
template <bool ATRANS>
__device__ __forceinline__ void mm64_compute(const float* __restrict__ A,
                                             const float* __restrict__ B,
                                             int i0, int j0,
                                             float (&acc)[4][4],
                                             float (*s1)[65], float (*s2)[65]) {
  const int t = threadIdx.x, tx = t & 15, ty = t >> 4;
  for (int k0 = 0; k0 < 256; k0 += 64) {
#pragma unroll
    for (int it = 0; it < 4; ++it) {
      const int f = t + 256 * it;          // 0..1023
      const int row = f >> 4, cc = (f & 15) * 4;
      float4 va;
      if (ATRANS)  // A used as A^T: element (k, i)
        va = *(const float4*)(A + (size_t)(k0 + row) * CCH + i0 + cc);
      else
        va = *(const float4*)(A + (size_t)(i0 + row) * CCH + k0 + cc);
      const float4 vb = *(const float4*)(B + (size_t)(k0 + row) * CCH + j0 + cc);
      s1[row][cc + 0] = va.x; s1[row][cc + 1] = va.y; s1[row][cc + 2] = va.z; s1[row][cc + 3] = va.w;
      s2[row][cc + 0] = vb.x; s2[row][cc + 1] = vb.y; s2[row][cc + 2] = vb.z; s2[row][cc + 3] = vb.w;
    }
    __syncthreads();
#pragma unroll 4
    for (int kk = 0; kk < 64; ++kk) {
      float ar[4], br[4];
#pragma unroll
      for (int i = 0; i < 4; ++i) ar[i] = ATRANS ? s1[kk][4 * ty + i] : s1[4 * ty + i][kk];
#pragma unroll
      for (int j = 0; j < 4; ++j) br[j] = s2[kk][4 * tx + j];
#pragma unroll
      for (int i = 0; i < 4; ++i)
#pragma unroll
        for (int j = 0; j < 4; ++j) acc[i][j] += ar[i] * br[j];
    }
    __syncthreads();
  }
}

// ---------- precompute A, Bm, t1, r, w1, c1 ----------
__global__ __launch_bounds__(256) void k_pre(const float* __restrict__ Ww,
                                             const float* __restrict__ gw,
                                             const float* __restrict__ phw,
                                             const float* __restrict__ thw,
                                             const float* __restrict__ gb,
                                             const float* __restrict__ phb,
                                             const float* __restrict__ thb,
                                             float* __restrict__ ws) {
  __shared__ float s1[64][65];
  __shared__ float s2[64][65];
  const int blk = blockIdx.x;
  const int t = threadIdx.x;
  if (blk < 32) {
    const int tb = blk & 15;
    const int i0 = (tb >> 2) * 64, j0 = (tb & 3) * 64;
    float acc[4][4] = {};
    if (blk < 16) mm64_compute<false>(Ww, gw, i0, j0, acc, s1, s2);   // A = Ww @ gw
    else          mm64_compute<true >(phw, thw, i0, j0, acc, s1, s2); // Bm = phw^T @ thw
    float* out = ws + (blk < 16 ? OFF_A : OFF_BM);
    const int tx = t & 15, ty = t >> 4;
#pragma unroll
    for (int i = 0; i < 4; ++i) {
      const float4 v = make_float4(acc[i][0], acc[i][1], acc[i][2], acc[i][3]);
      *(float4*)(out + (size_t)(i0 + 4 * ty + i) * CCH + j0 + 4 * tx) = v;
    }
  } else {
    float t1v = 0.f, rv = 0.f, w1v = 0.f;
    for (int k = 0; k < 256; ++k) {
      t1v += phw[k * CCH + t] * thb[k];
      rv  += thw[k * CCH + t] * phb[k];
      w1v += Ww[t * CCH + k] * gb[k];
    }
    ws[OFF_T1 + t] = t1v; ws[OFF_R + t] = rv; ws[OFF_W1 + t] = w1v;
    __shared__ float red[256];
    red[t] = phb[t] * thb[t];
    __syncthreads();
    for (int off = 128; off; off >>= 1) { if (t < off) red[t] += red[t + off]; __syncthreads(); }
    if (t == 0) ws[OFF_C1] = red[0];
  }
}

// ---------- per-batch Gram partials: Gpart[b][ks] (+ symmetric tile skip) ----------
__global__ __launch_bounds__(256) void k_gram(const float* __restrict__ xj, float* __restrict__ ws) {
  const int b = blockIdx.y;
  const int ks = blockIdx.x & 15;
  const int tl = blockIdx.x >> 4;                 // 0:(0,0) 1:(0,1) 2:(1,1)
  const int i0 = (tl == 2) ? 128 : 0;
  const int j0 = (tl == 0) ? 0 : 128;
  const float* __restrict__ X = xj + (size_t)b * CCH * NPIX;
  float* __restrict__ GP = ws + OFF_SHARED + (size_t)(b * 16 + ks) * (CCH * CCH);
  __shared__ float sa[128][33];
  __shared__ float sb[128][33];
  const int t = threadIdx.x, tx = t & 15, ty = t >> 4;
  const int k0 = ks * 256;
  float acc[2][2][4][4] = {};
  for (int kc = 0; kc < 256; kc += 32) {
#pragma unroll
    for (int it = 0; it < 4; ++it) {
      const int f = t + 256 * it;
      const int row = f >> 3, cc = (f & 7) * 4;
      const float4 va = *(const float4*)(X + (size_t)(i0 + row) * NPIX + k0 + kc + cc);
      const float4 vb = *(const float4*)(X + (size_t)(j0 + row) * NPIX + k0 + kc + cc);
      sa[row][cc + 0] = va.x; sa[row][cc + 1] = va.y; sa[row][cc + 2] = va.z; sa[row][cc + 3] = va.w;
      sb[row][cc + 0] = vb.x; sb[row][cc + 1] = vb.y; sb[row][cc + 2] = vb.z; sb[row][cc + 3] = vb.w;
    }
    __syncthreads();
#pragma unroll 4
    for (int kk = 0; kk < 32; ++kk) {
      float ar[2][4], br[2][4];
#pragma unroll
      for (int h = 0; h < 2; ++h)
#pragma unroll
        for (int i = 0; i < 4; ++i) {
          ar[h][i] = sa[h * 64 + 4 * ty + i][kk];
          br[h][i] = sb[h * 64 + 4 * tx + i][kk];
        }
#pragma unroll
      for (int ih = 0; ih < 2; ++ih)
#pragma unroll
        for (int jh = 0; jh < 2; ++jh)
#pragma unroll
          for (int i = 0; i < 4; ++i)
#pragma unroll
            for (int j = 0; j < 4; ++j)
              acc[ih][jh][i][j] += ar[ih][i] * br[jh][j];
    }
    __syncthreads();
  }
#pragma unroll
  for (int ih = 0; ih < 2; ++ih)
#pragma unroll
    for (int jh = 0; jh < 2; ++jh)
#pragma unroll
      for (int i = 0; i < 4; ++i) {
        const float4 v = make_float4(acc[ih][jh][i][0], acc[ih][jh][i][1],
                                     acc[ih][jh][i][2], acc[ih][jh][i][3]);
        *(float4*)(GP + (size_t)(i0 + ih * 64 + 4 * ty + i) * CCH + j0 + jh * 64 + 4 * tx) = v;
      }
}

// ---------- rowsums s_b ----------
__global__ __launch_bounds__(256) void k_rowsum(const float* __restrict__ xj, float* __restrict__ ws) {
  const int b = blockIdx.y;
  const int t = threadIdx.x;
  const int c = blockIdx.x * 16 + (t >> 4);
  const int tn = t & 15;
  const float4* row = (const float4*)(xj + ((size_t)b * CCH + c) * NPIX);
  float s = 0.f;
  for (int i = tn; i < 1024; i += 16) { const float4 v = row[i]; s += v.x + v.y + v.z + v.w; }
#pragma unroll
  for (int off = 8; off; off >>= 1) s += __shfl_down(s, off, 16);
  if (tn == 0) ws[OFF_S + b * CCH + c] = s;
}

// ---------- reduce Gram partials (with symmetric mirror) ----------
__global__ __launch_bounds__(256) void k_greduce(float* __restrict__ ws) {
  const int b = blockIdx.y, i = blockIdx.x, j = threadIdx.x;
  const float* GP = ws + OFF_SHARED + (size_t)b * 16 * 65536;
  const int src = (i >= 128 && j < 128) ? (j * CCH + i) : (i * CCH + j);
  float s = 0.f;
#pragma unroll 4
  for (int ks = 0; ks < 16; ++ks) s += GP[(size_t)ks * 65536 + src];
  ws[OFF_G + (size_t)b * 65536 + i * CCH + j] = s;
}

// ---------- K = A @ G (and u = A @ s) ----------
__global__ __launch_bounds__(256) void k_kmat(float* __restrict__ ws) {
  const int b = blockIdx.y;
  const int i0 = (blockIdx.x >> 2) * 64, j0 = (blockIdx.x & 3) * 64;
  const int t = threadIdx.x;
  const float* A = ws + OFF_A;
  const float* G = ws + OFF_G + (size_t)b * 65536;
  __shared__ float s1[64][65];
  __shared__ float s2[64][65];
  if (j0 == 0 && t < 64) {
    const float* sv = ws + OFF_S + b * CCH;
    float s = 0.f;
    for (int k = 0; k < 256; ++k) s += A[(i0 + t) * CCH + k] * sv[k];
    ws[OFF_U + b * CCH + i0 + t] = s;
  }
  float acc[4][4] = {};
  mm64_compute<false>(A, G, i0, j0, acc, s1, s2);
  float* K = ws + OFF_K + (size_t)b * 65536;
  const int tx = t & 15, ty = t >> 4;
#pragma unroll
  for (int i = 0; i < 4; ++i) {
    const float4 v = make_float4(acc[i][0], acc[i][1], acc[i][2], acc[i][3]);
    *(float4*)(K + (size_t)(i0 + 4 * ty + i) * CCH + j0 + 4 * tx) = v;
  }
}

// ---------- M = (1/N)(K Bm + u r^T + w1 v^T) + w1 r^T ; e ----------
__global__ __launch_bounds__(256) void k_mmat(const float* __restrict__ Wb, float* __restrict__ ws) {
  const int b = blockIdx.y;
  const int i0 = (blockIdx.x >> 2) * 64, j0 = (blockIdx.x & 3) * 64;
  const int t = threadIdx.x;
  const float* Kb = ws + OFF_K + (size_t)b * 65536;
  const float* Bm = ws + OFF_BM;
  const float* sv = ws + OFF_S + b * CCH;
  __shared__ float s1[64][65];
  __shared__ float s2[64][65];
  __shared__ float vs[64];
  __shared__ float red[256];
  __shared__ float sdt_s;
  red[t] = sv[t] * ws[OFF_T1 + t];
  __syncthreads();
  for (int off = 128; off; off >>= 1) { if (t < off) red[t] += red[t + off]; __syncthreads(); }
  if (t == 0) sdt_s = red[0];
  if (t < 64) {
    float s = 0.f;
    for (int k = 0; k < 256; ++k) s += Bm[k * CCH + j0 + t] * sv[k];
    vs[t] = s;
  }
  __syncthreads();
  float acc[4][4] = {};
  mm64_compute<false>(Kb, Bm, i0, j0, acc, s1, s2);
  const float c1 = ws[OFF_C1];
  const float sdt = sdt_s;
  const int tx = t & 15, ty = t >> 4;
  float* Mb = ws + OFF_M + (size_t)b * 65536;
#pragma unroll
  for (int i = 0; i < 4; ++i) {
    const int gi = i0 + 4 * ty + i;
    const float ui = ws[OFF_U + b * CCH + gi];
    const float w1i = ws[OFF_W1 + gi];
    float4 v;
    float* pv = &v.x;
#pragma unroll
    for (int q = 0; q < 4; ++q) {
      const int gj = j0 + 4 * tx + q;
      const float rj = ws[OFF_R + gj];
      pv[q] = (acc[i][q] + ui * rj + w1i * vs[4 * tx + q]) * INVN + w1i * rj;
    }
    *(float4*)(Mb + (size_t)gi * CCH + j0 + 4 * tx) = v;
  }
  if (j0 == 0 && t < 64) {
    const int gi = i0 + t;
    float s = 0.f;
    for (int k = 0; k < 256; ++k) s += Kb[gi * CCH + k] * ws[OFF_T1 + k];
    const float ui = ws[OFF_U + b * CCH + gi], w1i = ws[OFF_W1 + gi];
    ws[OFF_E + b * CCH + gi] = INVN * (s + c1 * ui + sdt * w1i) + c1 * w1i + Wb[gi];
  }
}

// ---------- Z = M @ Xi + e + Xi, with BN partial sums ----------
__global__ __launch_bounds__(256) void k_main(const float* __restrict__ xi, float* __restrict__ ws) {
  const int b = blockIdx.y;
  const int rt = blockIdx.x >> 5, ct = blockIdx.x & 31;
  const int c0 = rt * 128, n0 = ct * 128;
  const float* __restrict__ Xi = xi + (size_t)b * CCH * NPIX;
  const float* __restrict__ Mb = ws + OFF_M + (size_t)b * 65536;
  float* __restrict__ Z = ws + OFF_SHARED + (size_t)b * CCH * NPIX;
  __shared__ float sa[128][33];
  __shared__ float sbn[32][132];
  const int t = threadIdx.x, tx = t & 15, ty = t >> 4;
  float acc[2][2][4][4] = {};
  for (int k0 = 0; k0 < 256; k0 += 32) {
#pragma unroll
    for (int it = 0; it < 4; ++it) {
      const int f = t + 256 * it;
      {
        const int row = f >> 3, cc = (f & 7) * 4;
        const float4 v = *(const float4*)(Mb + (size_t)(c0 + row) * CCH + k0 + cc);
        sa[row][cc + 0] = v.x; sa[row][cc + 1] = v.y; sa[row][cc + 2] = v.z; sa[row][cc + 3] = v.w;
      }
      {
        const int kr = f >> 5, nn = (f & 31) * 4;
        *(float4*)&sbn[kr][nn] = *(const float4*)(Xi + (size_t)(k0 + kr) * NPIX + n0 + nn);
      }
    }
    __syncthreads();
#pragma unroll 4
    for (int kk = 0; kk < 32; ++kk) {
      float ar[2][4], br[2][4];
#pragma unroll
      for (int h = 0; h < 2; ++h) {
#pragma unroll
        for (int i = 0; i < 4; ++i) ar[h][i] = sa[h * 64 + 4 * ty + i][kk];
        const float4 bv = *(const float4*)&sbn[kk][h * 64 + 4 * tx];
        br[h][0] = bv.x; br[h][1] = bv.y; br[h][2] = bv.z; br[h][3] = bv.w;
      }
#pragma unroll
      for (int ih = 0; ih < 2; ++ih)
#pragma unroll
        for (int jh = 0; jh < 2; ++jh)
#pragma unroll
          for (int i = 0; i < 4; ++i)
#pragma unroll
            for (int j = 0; j < 4; ++j)
              acc[ih][jh][i][j] += ar[ih][i] * br[jh][j];
    }
    __syncthreads();
  }
  const float* __restrict__ E = ws + OFF_E + b * CCH;
  float psum[2][4] = {}; float psq[2][4] = {};
#pragma unroll
  for (int ih = 0; ih < 2; ++ih)
#pragma unroll
    for (int i = 0; i < 4; ++i) {
      const int gc = c0 + ih * 64 + 4 * ty + i;
      const float e = E[gc];
#pragma unroll
      for (int jh = 0; jh < 2; ++jh) {
        const float4 xr = *(const float4*)(Xi + (size_t)gc * NPIX + n0 + jh * 64 + 4 * tx);
        float4 zv;
        zv.x = acc[ih][jh][i][0] + e + xr.x;
        zv.y = acc[ih][jh][i][1] + e + xr.y;
        zv.z = acc[ih][jh][i][2] + e + xr.z;
        zv.w = acc[ih][jh][i][3] + e + xr.w;
        *(float4*)(Z + (size_t)gc * NPIX + n0 + jh * 64 + 4 * tx) = zv;
        psum[ih][i] += zv.x + zv.y + zv.z + zv.w;
        psq[ih][i]  += zv.x * zv.x + zv.y * zv.y + zv.z * zv.z + zv.w * zv.w;
      }
    }
  __syncthreads();
  float* red = &sa[0][0];
#pragma unroll
  for (int ih = 0; ih < 2; ++ih)
#pragma unroll
    for (int i = 0; i < 4; ++i)
      red[(ih * 64 + 4 * ty + i) * 16 + tx] = psum[ih][i];
  __syncthreads();
  if (t < 128) {
    float s = 0.f;
#pragma unroll
    for (int x = 0; x < 16; ++x) s += red[t * 16 + x];
    ws[OFF_ZPS + (size_t)(b * 32 + ct) * CCH + c0 + t] = s;
  }
  __syncthreads();
#pragma unroll
  for (int ih = 0; ih < 2; ++ih)
#pragma unroll
    for (int i = 0; i < 4; ++i)
      red[(ih * 64 + 4 * ty + i) * 16 + tx] = psq[ih][i];
  __syncthreads();
  if (t < 128) {
    float s = 0.f;
#pragma unroll
    for (int x = 0; x < 16; ++x) s += red[t * 16 + x];
    ws[OFF_ZPQ + (size_t)(b * 32 + ct) * CCH + c0 + t] = s;
  }
}

// ---------- BN stats -> scale/shift ----------
__global__ __launch_bounds__(256) void k_bnstats(const float* __restrict__ gamma,
                                                 const float* __restrict__ beta,
                                                 float* __restrict__ ws) {
  const int c = threadIdx.x;
  float s = 0.f, q = 0.f;
  for (int e = 0; e < 256; ++e) {
    s += ws[OFF_ZPS + (size_t)e * CCH + c];
    q += ws[OFF_ZPQ + (size_t)e * CCH + c];
  }
  const float mean = s * INVCNT;
  const float var = q * INVCNT - mean * mean;
  const float sc = gamma[c] * rsqrtf(var + 1e-5f);
  ws[OFF_SCALE + c] = sc;
  ws[OFF_SHIFT + c] = beta[c] - mean * sc;
}

// ---------- apply BN ----------
__global__ __launch_bounds__(256) void k_bnapply(const float* __restrict__ ws, float* __restrict__ out) {
  const size_t stride = (size_t)gridDim.x * blockDim.x;
  const float* Z = ws + OFF_SHARED;
  const size_t n4 = (size_t)NB * CCH * NPIX / 4;
  for (size_t i4 = (size_t)blockIdx.x * blockDim.x + threadIdx.x; i4 < n4; i4 += stride) {
    const int c = (int)((i4 >> 10) & 255);
    const float sc = ws[OFF_SCALE + c], sh = ws[OFF_SHIFT + c];
    float4 z = ((const float4*)Z)[i4];
    z.x = z.x * sc + sh; z.y = z.y * sc + sh; z.z = z.z * sc + sh; z.w = z.w * sc + sh;
    ((float4*)out)[i4] = z;
  }
}

extern "C" void kernel_launch(void* const* d_in, const int* in_sizes, int n_in,
                              void* d_out, int out_size, void* d_ws, size_t ws_size,
                              hipStream_t stream) {
  const float* xi  = (const float*)d_in[0];
  const float* xj  = (const float*)d_in[1];
  const float* gw  = (const float*)d_in[2];
  const float* gb  = (const float*)d_in[3];
  const float* thw = (const float*)d_in[4];
  const float* thb = (const float*)d_in[5];
  const float* phw = (const float*)d_in[6];
  const float* phb = (const float*)d_in[7];
  const float* Ww  = (const float*)d_in[8];
  const float* Wb  = (const float*)d_in[9];
  const float* gamma = (const float*)d_in[10];
  const float* beta  = (const float*)d_in[11];
  float* ws = (float*)d_ws;
  float* out = (float*)d_out;

  k_pre<<<33, 256, 0, stream>>>(Ww, gw, phw, thw, gb, phb, thb, ws);
  k_gram<<<dim3(48, 8), 256, 0, stream>>>(xj, ws);
  k_rowsum<<<dim3(16, 8), 256, 0, stream>>>(xj, ws);
  k_greduce<<<dim3(256, 8), 256, 0, stream>>>(ws);
  k_kmat<<<dim3(16, 8), 256, 0, stream>>>(ws);
  k_mmat<<<dim3(16, 8), 256, 0, stream>>>(Wb, ws);
  k_main<<<dim3(64, 8), 256, 0, stream>>>(xi, ws);
  k_bnstats<<<1, 256, 0, stream>>>(gamma, beta, ws);
  k_bnapply<<<2048, 256, 0, stream>>>(ws, out);
}

// Round 3
// 176.513 us; speedup vs baseline: 1.5272x; 1.5272x over previous
//
#include <hip/hip_runtime.h>
#include <cstddef>

#define CCH 256
#define NPIX 4096
#define NB 8
#define INVCNT (1.0f/32768.0f)
#define INVN (1.0f/4096.0f)

typedef __bf16 bf16_t;
typedef __attribute__((ext_vector_type(8))) __bf16 bf16x8;
typedef __attribute__((ext_vector_type(4))) __bf16 bf16x4;
typedef __attribute__((ext_vector_type(4))) float f32x4;

// ---- workspace layout (float offsets) ----
// M' is bf16: 8 * 65536 bf16 = 262144 float-equivalents (R2 bug: reserved 131072 -> clobbered E/RSP/ZPS)
#define OFF_S      0u          // 8*256 rowsums of Xj
#define OFF_A      2048u       // A = W_w @ g_w       (256x256 fp32)
#define OFF_BM     67584u      // Bm = phi_w^T theta_w(256x256 fp32)
#define OFF_T1     133120u     // t1 = phi_w^T theta_b
#define OFF_R      133376u     // r  = theta_w^T phi_b
#define OFF_W1     133632u     // w1 = W_w @ g_b
#define OFF_C1     133888u     // c1 = phi_b . theta_b
#define OFF_G      134144u     // G  8 x 256x256 fp32
#define OFF_K      658432u     // K = A @ G  8 x 256x256 fp32
#define OFF_U      1182720u    // u = A @ s  8 x 256
#define OFF_MP     1184768u    // M' = M + I  8 x 256x256 bf16  (262144 floats)
#define OFF_E      1446912u    // e  8 x 256
#define OFF_RSP    1448960u    // rowsum partials 8 x 16 x 256
#define OFF_ZPS    1481728u    // bn partial sums   [entry 256][c 256]
#define OFF_ZPQ    1547264u    // bn partial sumsq
#define OFF_SCALE  1612800u
#define OFF_SHIFT  1613056u
#define OFF_BIG    1613312u    // union: Gpart (8*16*3*16384 fp32) then Xi_t (8*4096*256 bf16)

__device__ __forceinline__ void pack8(const float4& x, const float4& y, bf16x8& o) {
  o[0]=(bf16_t)x.x; o[1]=(bf16_t)x.y; o[2]=(bf16_t)x.z; o[3]=(bf16_t)x.w;
  o[4]=(bf16_t)y.x; o[5]=(bf16_t)y.y; o[6]=(bf16_t)y.z; o[7]=(bf16_t)y.w;
}

// ---------- generic 64x64-tile NN/TN fp32 matmul over K=256 ----------
template <bool ATRANS>
__device__ __forceinline__ void mm64_compute(const float* __restrict__ A,
                                             const float* __restrict__ B,
                                             int i0, int j0,
                                             float (&acc)[4][4],
                                             float (*s1)[65], float (*s2)[65]) {
  const int t = threadIdx.x, tx = t & 15, ty = t >> 4;
  for (int k0 = 0; k0 < 256; k0 += 64) {
#pragma unroll
    for (int it = 0; it < 4; ++it) {
      const int f = t + 256 * it;
      const int row = f >> 4, cc = (f & 15) * 4;
      float4 va;
      if (ATRANS)
        va = *(const float4*)(A + (size_t)(k0 + row) * CCH + i0 + cc);
      else
        va = *(const float4*)(A + (size_t)(i0 + row) * CCH + k0 + cc);
      const float4 vb = *(const float4*)(B + (size_t)(k0 + row) * CCH + j0 + cc);
      s1[row][cc + 0] = va.x; s1[row][cc + 1] = va.y; s1[row][cc + 2] = va.z; s1[row][cc + 3] = va.w;
      s2[row][cc + 0] = vb.x; s2[row][cc + 1] = vb.y; s2[row][cc + 2] = vb.z; s2[row][cc + 3] = vb.w;
    }
    __syncthreads();
#pragma unroll 4
    for (int kk = 0; kk < 64; ++kk) {
      float ar[4], br[4];
#pragma unroll
      for (int i = 0; i < 4; ++i) ar[i] = ATRANS ? s1[kk][4 * ty + i] : s1[4 * ty + i][kk];
#pragma unroll
      for (int j = 0; j < 4; ++j) br[j] = s2[kk][4 * tx + j];
#pragma unroll
      for (int i = 0; i < 4; ++i)
#pragma unroll
        for (int j = 0; j < 4; ++j) acc[i][j] += ar[i] * br[j];
    }
    __syncthreads();
  }
}

// ---------- precompute A, Bm, t1, r, w1, c1 ----------
__global__ __launch_bounds__(256) void k_pre(const float* __restrict__ Ww,
                                             const float* __restrict__ gw,
                                             const float* __restrict__ phw,
                                             const float* __restrict__ thw,
                                             const float* __restrict__ gb,
                                             const float* __restrict__ phb,
                                             const float* __restrict__ thb,
                                             float* __restrict__ ws) {
  __shared__ float s1[64][65];
  __shared__ float s2[64][65];
  const int blk = blockIdx.x;
  const int t = threadIdx.x;
  if (blk < 32) {
    const int tb = blk & 15;
    const int i0 = (tb >> 2) * 64, j0 = (tb & 3) * 64;
    float acc[4][4] = {};
    if (blk < 16) mm64_compute<false>(Ww, gw, i0, j0, acc, s1, s2);
    else          mm64_compute<true >(phw, thw, i0, j0, acc, s1, s2);
    float* out = ws + (blk < 16 ? OFF_A : OFF_BM);
    const int tx = t & 15, ty = t >> 4;
#pragma unroll
    for (int i = 0; i < 4; ++i) {
      const float4 v = make_float4(acc[i][0], acc[i][1], acc[i][2], acc[i][3]);
      *(float4*)(out + (size_t)(i0 + 4 * ty + i) * CCH + j0 + 4 * tx) = v;
    }
  } else {
    float t1v = 0.f, rv = 0.f, w1v = 0.f;
    for (int k = 0; k < 256; ++k) {
      t1v += phw[k * CCH + t] * thb[k];
      rv  += thw[k * CCH + t] * phb[k];
      w1v += Ww[t * CCH + k] * gb[k];
    }
    ws[OFF_T1 + t] = t1v; ws[OFF_R + t] = rv; ws[OFF_W1 + t] = w1v;
    __shared__ float red[256];
    red[t] = phb[t] * thb[t];
    __syncthreads();
    for (int off = 128; off; off >>= 1) { if (t < off) red[t] += red[t + off]; __syncthreads(); }
    if (t == 0) ws[OFF_C1] = red[0];
  }
}

// ---------- Gram partials via MFMA (+ fused rowsums) ----------
__global__ __launch_bounds__(256) void k_gram(const float* __restrict__ xj, float* __restrict__ ws) {
  const int b = blockIdx.y;
  const int ks = blockIdx.x & 15;
  const int tl = blockIdx.x >> 4;                 // 0:(0,0) 1:(0,1) 2:(1,1)
  const int i0 = (tl == 2) ? 128 : 0;
  const int j0 = (tl == 0) ? 0 : 128;
  const float* __restrict__ X = xj + (size_t)b * CCH * NPIX;
  __shared__ __align__(16) bf16_t sA[128][40];
  __shared__ __align__(16) bf16_t sB[128][40];
  const int t = threadIdx.x;
  const int w = t >> 6, lane = t & 63;
  const f32x4 z4 = {0.f, 0.f, 0.f, 0.f};
  f32x4 acc[2][8];
#pragma unroll
  for (int fr = 0; fr < 2; ++fr)
#pragma unroll
    for (int fc = 0; fc < 8; ++fc) acc[fr][fc] = z4;
  float rsum = 0.f;
  const int k0 = ks * 256;
  const int srow = t >> 1, sh16 = (t & 1) * 16;
  const bool haveB = (tl == 1);
  for (int kc = 0; kc < 256; kc += 32) {
    const float* pa = X + (size_t)(i0 + srow) * NPIX + k0 + kc + sh16;
    const float4 a0 = *(const float4*)pa;
    const float4 a1 = *(const float4*)(pa + 4);
    const float4 a2 = *(const float4*)(pa + 8);
    const float4 a3 = *(const float4*)(pa + 12);
    rsum += a0.x + a0.y + a0.z + a0.w + a1.x + a1.y + a1.z + a1.w
          + a2.x + a2.y + a2.z + a2.w + a3.x + a3.y + a3.z + a3.w;
    bf16x8 u0, u1;
    pack8(a0, a1, u0); pack8(a2, a3, u1);
    bf16x8 w0, w1;
    if (haveB) {
      const float* pb = X + (size_t)(j0 + srow) * NPIX + k0 + kc + sh16;
      const float4 b0 = *(const float4*)pb;
      const float4 b1 = *(const float4*)(pb + 4);
      const float4 b2 = *(const float4*)(pb + 8);
      const float4 b3 = *(const float4*)(pb + 12);
      pack8(b0, b1, w0); pack8(b2, b3, w1);
    }
    __syncthreads();
    *(bf16x8*)&sA[srow][sh16] = u0;
    *(bf16x8*)&sA[srow][sh16 + 8] = u1;
    if (haveB) {
      *(bf16x8*)&sB[srow][sh16] = w0;
      *(bf16x8*)&sB[srow][sh16 + 8] = w1;
    }
    __syncthreads();
    bf16_t (*SB)[40] = haveB ? sB : sA;
    const int fcol = 8 * (lane >> 4);
    const int lr = lane & 15;
    const bf16x8 af0 = *(const bf16x8*)&sA[32 * w + lr][fcol];
    const bf16x8 af1 = *(const bf16x8*)&sA[32 * w + 16 + lr][fcol];
#pragma unroll
    for (int fc = 0; fc < 8; ++fc) {
      const bf16x8 bv = *(const bf16x8*)&SB[16 * fc + lr][fcol];
      acc[0][fc] = __builtin_amdgcn_mfma_f32_16x16x32_bf16(af0, bv, acc[0][fc], 0, 0, 0);
      acc[1][fc] = __builtin_amdgcn_mfma_f32_16x16x32_bf16(af1, bv, acc[1][fc], 0, 0, 0);
    }
  }
  if (tl != 1) {
    const float o = __shfl_down(rsum, 1);
    if (!(t & 1)) ws[OFF_RSP + ((size_t)(b * 16 + ks)) * CCH + i0 + srow] = rsum + o;
  }
  float* GP = ws + OFF_BIG + ((size_t)((b * 16 + ks) * 3 + tl)) * 16384;
  const int rbase = 32 * w + ((lane >> 4) << 2);
  const int col = lane & 15;
#pragma unroll
  for (int fr = 0; fr < 2; ++fr)
#pragma unroll
    for (int fc = 0; fc < 8; ++fc)
#pragma unroll
      for (int reg = 0; reg < 4; ++reg)
        GP[(size_t)(rbase + 16 * fr + reg) * 128 + 16 * fc + col] = acc[fr][fc][reg];
}

// ---------- reduce Gram partials + mirror + finalize rowsums ----------
__global__ __launch_bounds__(256) void k_greduce(float* __restrict__ ws) {
  const int b = blockIdx.y, i = blockIdx.x, j = threadIdx.x;
  const float* BP = ws + OFF_BIG;
  const size_t base = (size_t)b * 48;
  int tl, idx;
  if (i < 128) {
    if (j < 128) { tl = 0; idx = i * 128 + j; }
    else         { tl = 1; idx = i * 128 + (j - 128); }
  } else {
    if (j < 128) { tl = 1; idx = j * 128 + (i - 128); }
    else         { tl = 2; idx = (i - 128) * 128 + (j - 128); }
  }
  float s = 0.f;
#pragma unroll 4
  for (int ks = 0; ks < 16; ++ks) s += BP[(base + ks * 3 + tl) * 16384 + idx];
  ws[OFF_G + (size_t)b * 65536 + i * CCH + j] = s;
  if (j < 16) {
    float v = ws[OFF_RSP + ((size_t)(b * 16 + j)) * CCH + i];
#pragma unroll
    for (int off = 8; off; off >>= 1) v += __shfl_down(v, off, 16);
    if (j == 0) ws[OFF_S + b * CCH + i] = v;
  }
}

// ---------- K = A @ G (and u = A @ s) ----------
__global__ __launch_bounds__(256) void k_kmat(float* __restrict__ ws) {
  const int b = blockIdx.y;
  const int i0 = (blockIdx.x >> 2) * 64, j0 = (blockIdx.x & 3) * 64;
  const int t = threadIdx.x;
  const float* A = ws + OFF_A;
  const float* G = ws + OFF_G + (size_t)b * 65536;
  __shared__ float s1[64][65];
  __shared__ float s2[64][65];
  if (j0 == 0 && t < 64) {
    const float* sv = ws + OFF_S + b * CCH;
    float s = 0.f;
    for (int k = 0; k < 256; ++k) s += A[(i0 + t) * CCH + k] * sv[k];
    ws[OFF_U + b * CCH + i0 + t] = s;
  }
  float acc[4][4] = {};
  mm64_compute<false>(A, G, i0, j0, acc, s1, s2);
  float* K = ws + OFF_K + (size_t)b * 65536;
  const int tx = t & 15, ty = t >> 4;
#pragma unroll
  for (int i = 0; i < 4; ++i) {
    const float4 v = make_float4(acc[i][0], acc[i][1], acc[i][2], acc[i][3]);
    *(float4*)(K + (size_t)(i0 + 4 * ty + i) * CCH + j0 + 4 * tx) = v;
  }
}

// ---------- M' = (1/N)(K Bm + u r^T + w1 v^T) + w1 r^T + I (bf16) ; e ----------
__global__ __launch_bounds__(256) void k_mmat(const float* __restrict__ Wb, float* __restrict__ ws) {
  const int b = blockIdx.y;
  const int i0 = (blockIdx.x >> 2) * 64, j0 = (blockIdx.x & 3) * 64;
  const int t = threadIdx.x;
  const float* Kb = ws + OFF_K + (size_t)b * 65536;
  const float* Bm = ws + OFF_BM;
  const float* sv = ws + OFF_S + b * CCH;
  __shared__ float s1[64][65];
  __shared__ float s2[64][65];
  __shared__ float vs[64];
  __shared__ float red[256];
  __shared__ float sdt_s;
  red[t] = sv[t] * ws[OFF_T1 + t];
  __syncthreads();
  for (int off = 128; off; off >>= 1) { if (t < off) red[t] += red[t + off]; __syncthreads(); }
  if (t == 0) sdt_s = red[0];
  if (t < 64) {
    float s = 0.f;
    for (int k = 0; k < 256; ++k) s += Bm[k * CCH + j0 + t] * sv[k];
    vs[t] = s;
  }
  __syncthreads();
  float acc[4][4] = {};
  mm64_compute<false>(Kb, Bm, i0, j0, acc, s1, s2);
  const float c1 = ws[OFF_C1];
  const float sdt = sdt_s;
  const int tx = t & 15, ty = t >> 4;
  bf16_t* Mb = (bf16_t*)(ws + OFF_MP) + (size_t)b * 65536;
#pragma unroll
  for (int i = 0; i < 4; ++i) {
    const int gi = i0 + 4 * ty + i;
    const float ui = ws[OFF_U + b * CCH + gi];
    const float w1i = ws[OFF_W1 + gi];
    bf16x4 mv;
#pragma unroll
    for (int q = 0; q < 4; ++q) {
      const int gj = j0 + 4 * tx + q;
      const float rj = ws[OFF_R + gj];
      float v = (acc[i][q] + ui * rj + w1i * vs[4 * tx + q]) * INVN + w1i * rj;
      if (gi == gj) v += 1.0f;
      mv[q] = (bf16_t)v;
    }
    *(bf16x4*)&Mb[(size_t)gi * CCH + j0 + 4 * tx] = mv;
  }
  if (j0 == 0 && t < 64) {
    const int gi = i0 + t;
    float s = 0.f;
    for (int k = 0; k < 256; ++k) s += Kb[gi * CCH + k] * ws[OFF_T1 + k];
    const float ui = ws[OFF_U + b * CCH + gi], w1i = ws[OFF_W1 + gi];
    ws[OFF_E + b * CCH + gi] = INVN * (s + c1 * ui + sdt * w1i) + c1 * w1i + Wb[gi];
  }
}

// ---------- transpose-convert Xi -> Xi_t bf16 [b][n][c] ----------
__global__ __launch_bounds__(256) void k_cvtT(const float* __restrict__ xi, float* __restrict__ ws) {
  const int b = blockIdx.y;
  const int c0 = (blockIdx.x & 3) * 64;
  const int n0 = (blockIdx.x >> 2) * 64;
  __shared__ __align__(16) bf16_t st[64][72];
  const float* X = xi + (size_t)b * CCH * NPIX;
  const int t = threadIdx.x;
  const int r = t >> 4, c4 = (t & 15) * 4;
#pragma unroll
  for (int it = 0; it < 4; ++it) {
    const int row = r + 16 * it;
    const float4 v = *(const float4*)(X + (size_t)(c0 + row) * NPIX + n0 + c4);
    st[row][c4 + 0] = (bf16_t)v.x; st[row][c4 + 1] = (bf16_t)v.y;
    st[row][c4 + 2] = (bf16_t)v.z; st[row][c4 + 3] = (bf16_t)v.w;
  }
  __syncthreads();
  bf16_t* Xit = (bf16_t*)(ws + OFF_BIG) + (size_t)b * NPIX * CCH;
  const int nr = t >> 2, cc = (t & 3) * 16;
  bf16x8 o0, o1;
#pragma unroll
  for (int j = 0; j < 8; ++j) o0[j] = st[cc + j][nr];
#pragma unroll
  for (int j = 0; j < 8; ++j) o1[j] = st[cc + 8 + j][nr];
  *(bf16x8*)(Xit + (size_t)(n0 + nr) * CCH + c0 + cc) = o0;
  *(bf16x8*)(Xit + (size_t)(n0 + nr) * CCH + c0 + cc + 8) = o1;
}

// ---------- Z^T tiles via MFMA: APPLY=0 -> BN partials; APPLY=1 -> write out ----------
template <int APPLY>
__global__ __launch_bounds__(512) void k_zmm(float* __restrict__ ws, float* __restrict__ out) {
  const int b = blockIdx.y, nblk = blockIdx.x;
  const int n0 = nblk * 128;
  const int t = threadIdx.x;
  const int w = t >> 6, lane = t & 63;
  const int rg = w >> 1, cg = w & 1;
  __shared__ __align__(16) bf16_t sA[128][40];
  __shared__ __align__(16) bf16_t sB[256][40];
  __shared__ float sC1[256], sC2[256];
  __shared__ float redS[8][128], redQ[8][128];
  if (t < 256) {
    const float e = ws[OFF_E + b * CCH + t];
    if (APPLY) {
      const float sc = ws[OFF_SCALE + t];
      sC1[t] = sc;
      sC2[t] = e * sc + ws[OFF_SHIFT + t];
    } else {
      sC1[t] = e;
    }
  }
  const bf16_t* Xit = (const bf16_t*)(ws + OFF_BIG) + (size_t)b * NPIX * CCH;
  const bf16_t* Mp = (const bf16_t*)(ws + OFF_MP) + (size_t)b * 65536;
  const f32x4 z4 = {0.f, 0.f, 0.f, 0.f};
  f32x4 acc[2][8];
#pragma unroll
  for (int fr = 0; fr < 2; ++fr)
#pragma unroll
    for (int fc = 0; fc < 8; ++fc) acc[fr][fc] = z4;
  const int arow = t >> 2, achk = (t & 3) * 8;
  for (int k0 = 0; k0 < 256; k0 += 32) {
    const bf16x8 va  = *(const bf16x8*)(Xit + (size_t)(n0 + arow) * CCH + k0 + achk);
    const bf16x8 vb0 = *(const bf16x8*)(Mp + (size_t)arow * CCH + k0 + achk);
    const bf16x8 vb1 = *(const bf16x8*)(Mp + (size_t)(128 + arow) * CCH + k0 + achk);
    __syncthreads();
    *(bf16x8*)&sA[arow][achk] = va;
    *(bf16x8*)&sB[arow][achk] = vb0;
    *(bf16x8*)&sB[128 + arow][achk] = vb1;
    __syncthreads();
    const int fcol = 8 * (lane >> 4);
    const int lr = lane & 15;
    const bf16x8 af0 = *(const bf16x8*)&sA[32 * rg + lr][fcol];
    const bf16x8 af1 = *(const bf16x8*)&sA[32 * rg + 16 + lr][fcol];
#pragma unroll
    for (int fc = 0; fc < 8; ++fc) {
      const bf16x8 bv = *(const bf16x8*)&sB[128 * cg + 16 * fc + lr][fcol];
      acc[0][fc] = __builtin_amdgcn_mfma_f32_16x16x32_bf16(af0, bv, acc[0][fc], 0, 0, 0);
      acc[1][fc] = __builtin_amdgcn_mfma_f32_16x16x32_bf16(af1, bv, acc[1][fc], 0, 0, 0);
    }
  }
  if (APPLY) {
#pragma unroll
    for (int fc = 0; fc < 8; ++fc) {
      const int c = 128 * cg + 16 * fc + (lane & 15);
      const float sc = sC1[c], b2 = sC2[c];
      float* op = out + ((size_t)b * CCH + c) * NPIX + n0 + 32 * rg + ((lane >> 4) << 2);
#pragma unroll
      for (int fr = 0; fr < 2; ++fr) {
        float4 v;
        v.x = acc[fr][fc][0] * sc + b2;
        v.y = acc[fr][fc][1] * sc + b2;
        v.z = acc[fr][fc][2] * sc + b2;
        v.w = acc[fr][fc][3] * sc + b2;
        *(float4*)(op + 16 * fr) = v;
      }
    }
  } else {
    float ps[8], pq[8];
#pragma unroll
    for (int fc = 0; fc < 8; ++fc) {
      const int c = 128 * cg + 16 * fc + (lane & 15);
      const float e = sC1[c];
      float s = 0.f, q = 0.f;
#pragma unroll
      for (int fr = 0; fr < 2; ++fr)
#pragma unroll
        for (int reg = 0; reg < 4; ++reg) {
          const float z = acc[fr][fc][reg] + e;
          s += z; q += z * z;
        }
      s += __shfl_xor(s, 16); s += __shfl_xor(s, 32);
      q += __shfl_xor(q, 16); q += __shfl_xor(q, 32);
      ps[fc] = s; pq[fc] = q;
    }
    if (lane < 16) {
#pragma unroll
      for (int fc = 0; fc < 8; ++fc) {
        redS[w][16 * fc + lane] = ps[fc];
        redQ[w][16 * fc + lane] = pq[fc];
      }
    }
    __syncthreads();
    if (t < 256) {
      const int cg2 = t >> 7, c = t & 127;
      float s = 0.f, q = 0.f;
#pragma unroll
      for (int rg2 = 0; rg2 < 4; ++rg2) {
        s += redS[rg2 * 2 + cg2][c];
        q += redQ[rg2 * 2 + cg2][c];
      }
      ws[OFF_ZPS + ((size_t)(b * 32 + nblk)) * CCH + (cg2 << 7) + c] = s;
      ws[OFF_ZPQ + ((size_t)(b * 32 + nblk)) * CCH + (cg2 << 7) + c] = q;
    }
  }
}

// ---------- BN stats -> scale/shift ----------
__global__ __launch_bounds__(256) void k_bnstats(const float* __restrict__ gamma,
                                                 const float* __restrict__ beta,
                                                 float* __restrict__ ws) {
  const int c = threadIdx.x;
  float s = 0.f, q = 0.f;
  for (int e = 0; e < 256; ++e) {
    s += ws[OFF_ZPS + (size_t)e * CCH + c];
    q += ws[OFF_ZPQ + (size_t)e * CCH + c];
  }
  const float mean = s * INVCNT;
  const float var = q * INVCNT - mean * mean;
  const float sc = gamma[c] * rsqrtf(var + 1e-5f);
  ws[OFF_SCALE + c] = sc;
  ws[OFF_SHIFT + c] = beta[c] - mean * sc;
}

extern "C" void kernel_launch(void* const* d_in, const int* in_sizes, int n_in,
                              void* d_out, int out_size, void* d_ws, size_t ws_size,
                              hipStream_t stream) {
  const float* xi  = (const float*)d_in[0];
  const float* xj  = (const float*)d_in[1];
  const float* gw  = (const float*)d_in[2];
  const float* gb  = (const float*)d_in[3];
  const float* thw = (const float*)d_in[4];
  const float* thb = (const float*)d_in[5];
  const float* phw = (const float*)d_in[6];
  const float* phb = (const float*)d_in[7];
  const float* Ww  = (const float*)d_in[8];
  const float* Wb  = (const float*)d_in[9];
  const float* gamma = (const float*)d_in[10];
  const float* beta  = (const float*)d_in[11];
  float* ws = (float*)d_ws;
  float* out = (float*)d_out;

  k_pre<<<33, 256, 0, stream>>>(Ww, gw, phw, thw, gb, phb, thb, ws);
  k_gram<<<dim3(48, 8), 256, 0, stream>>>(xj, ws);
  k_greduce<<<dim3(256, 8), 256, 0, stream>>>(ws);
  k_kmat<<<dim3(16, 8), 256, 0, stream>>>(ws);
  k_mmat<<<dim3(16, 8), 256, 0, stream>>>(Wb, ws);
  k_cvtT<<<dim3(256, 8), 256, 0, stream>>>(xi, ws);
  k_zmm<0><<<dim3(32, 8), 512, 0, stream>>>(ws, out);
  k_bnstats<<<1, 256, 0, stream>>>(gamma, beta, ws);
  k_zmm<1><<<dim3(32, 8), 512, 0, stream>>>(ws, out);
}

// Round 4
// 170.847 us; speedup vs baseline: 1.5778x; 1.0332x over previous
//
#include <hip/hip_runtime.h>
#include <cstddef>

#define CCH 256
#define NPIX 4096
#define NB 8
#define INVCNT (1.0f/32768.0f)
#define INVN (1.0f/4096.0f)

typedef __bf16 bf16_t;
typedef __attribute__((ext_vector_type(8))) __bf16 bf16x8;
typedef __attribute__((ext_vector_type(4))) __bf16 bf16x4;
typedef __attribute__((ext_vector_type(4))) float f32x4;

// ---- workspace layout (float offsets) ----
// NOTE: Gpart and Xi_t are now CONCURRENT (mega kernel) -> separate regions, no union.
#define OFF_S      0u          // 8*256 rowsums of Xj
#define OFF_A      2048u       // A = W_w @ g_w       (256x256 fp32)
#define OFF_BM     67584u      // Bm = phi_w^T theta_w(256x256 fp32)
#define OFF_T1     133120u
#define OFF_R      133376u
#define OFF_W1     133632u
#define OFF_C1     133888u
#define OFF_G      134144u     // G  8 x 256x256 fp32
#define OFF_K      658432u     // K = A @ G
#define OFF_U      1182720u    // u = A @ s
#define OFF_MP     1184768u    // M' bf16 8x65536 = 262144 float-equiv
#define OFF_E      1446912u    // e  8 x 256
#define OFF_RSP    1448960u    // rowsum partials 8 x 16 x 256
#define OFF_ZPS    1481728u    // bn partial sums   [512 entries][256 c]
#define OFF_ZPQ    1612800u    // bn partial sumsq
#define OFF_SCALE  1743872u
#define OFF_SHIFT  1744128u
#define OFF_GP     1744384u    // Gram partials 8*16*3*16384 fp32 = 6291456
#define OFF_XIT    8035840u    // Xi_t bf16 8*4096*256 = 4194304 float-equiv

__device__ __forceinline__ void pack8(const float4& x, const float4& y, bf16x8& o) {
  o[0]=(bf16_t)x.x; o[1]=(bf16_t)x.y; o[2]=(bf16_t)x.z; o[3]=(bf16_t)x.w;
  o[4]=(bf16_t)y.x; o[5]=(bf16_t)y.y; o[6]=(bf16_t)y.z; o[7]=(bf16_t)y.w;
}

__device__ __forceinline__ void ld4(const float* p, float4& a0, float4& a1, float4& a2, float4& a3) {
  a0 = *(const float4*)p;       a1 = *(const float4*)(p + 4);
  a2 = *(const float4*)(p + 8); a3 = *(const float4*)(p + 12);
}

// ---------- generic 64x64-tile NN/TN fp32 matmul over K=256 ----------
template <bool ATRANS>
__device__ __forceinline__ void mm64_compute(const float* __restrict__ A,
                                             const float* __restrict__ B,
                                             int i0, int j0,
                                             float (&acc)[4][4],
                                             float (*s1)[65], float (*s2)[65]) {
  const int t = threadIdx.x, tx = t & 15, ty = t >> 4;
  for (int k0 = 0; k0 < 256; k0 += 64) {
#pragma unroll
    for (int it = 0; it < 4; ++it) {
      const int f = t + 256 * it;
      const int row = f >> 4, cc = (f & 15) * 4;
      float4 va;
      if (ATRANS)
        va = *(const float4*)(A + (size_t)(k0 + row) * CCH + i0 + cc);
      else
        va = *(const float4*)(A + (size_t)(i0 + row) * CCH + k0 + cc);
      const float4 vb = *(const float4*)(B + (size_t)(k0 + row) * CCH + j0 + cc);
      s1[row][cc + 0] = va.x; s1[row][cc + 1] = va.y; s1[row][cc + 2] = va.z; s1[row][cc + 3] = va.w;
      s2[row][cc + 0] = vb.x; s2[row][cc + 1] = vb.y; s2[row][cc + 2] = vb.z; s2[row][cc + 3] = vb.w;
    }
    __syncthreads();
#pragma unroll 4
    for (int kk = 0; kk < 64; ++kk) {
      float ar[4], br[4];
#pragma unroll
      for (int i = 0; i < 4; ++i) ar[i] = ATRANS ? s1[kk][4 * ty + i] : s1[4 * ty + i][kk];
#pragma unroll
      for (int j = 0; j < 4; ++j) br[j] = s2[kk][4 * tx + j];
#pragma unroll
      for (int i = 0; i < 4; ++i)
#pragma unroll
        for (int j = 0; j < 4; ++j) acc[i][j] += ar[i] * br[j];
    }
    __syncthreads();
  }
}

// ---------- mega-kernel bodies ----------
__device__ void pre_body(int blk, const float* Ww, const float* gw, const float* phw,
                         const float* thw, const float* gb, const float* phb,
                         const float* thb, float* ws, unsigned char* SMEM) {
  const int t = threadIdx.x;
  if (blk < 32) {
    float (*s1)[65] = (float(*)[65])SMEM;
    float (*s2)[65] = (float(*)[65])(SMEM + 16640);
    const int tb = blk & 15;
    const int i0 = (tb >> 2) * 64, j0 = (tb & 3) * 64;
    float acc[4][4] = {};
    if (blk < 16) mm64_compute<false>(Ww, gw, i0, j0, acc, s1, s2);
    else          mm64_compute<true >(phw, thw, i0, j0, acc, s1, s2);
    float* out = ws + (blk < 16 ? OFF_A : OFF_BM);
    const int tx = t & 15, ty = t >> 4;
#pragma unroll
    for (int i = 0; i < 4; ++i) {
      const float4 v = make_float4(acc[i][0], acc[i][1], acc[i][2], acc[i][3]);
      *(float4*)(out + (size_t)(i0 + 4 * ty + i) * CCH + j0 + 4 * tx) = v;
    }
  } else {
    float t1v = 0.f, rv = 0.f, w1v = 0.f;
    for (int k = 0; k < 256; ++k) {
      t1v += phw[k * CCH + t] * thb[k];
      rv  += thw[k * CCH + t] * phb[k];
      w1v += Ww[t * CCH + k] * gb[k];
    }
    ws[OFF_T1 + t] = t1v; ws[OFF_R + t] = rv; ws[OFF_W1 + t] = w1v;
    float* red = (float*)SMEM;
    red[t] = phb[t] * thb[t];
    __syncthreads();
    for (int off = 128; off; off >>= 1) { if (t < off) red[t] += red[t + off]; __syncthreads(); }
    if (t == 0) ws[OFF_C1] = red[0];
  }
}

__device__ void cvtT_body(int bx, int b, const float* __restrict__ xi,
                          float* __restrict__ ws, unsigned char* SMEM) {
  bf16_t (*st)[72] = (bf16_t(*)[72])SMEM;
  const int c0 = (bx & 3) * 64;
  const int n0 = (bx >> 2) * 64;
  const float* X = xi + (size_t)b * CCH * NPIX;
  const int t = threadIdx.x;
  const int r = t >> 4, c4 = (t & 15) * 4;
#pragma unroll
  for (int it = 0; it < 4; ++it) {
    const int row = r + 16 * it;
    const float4 v = *(const float4*)(X + (size_t)(c0 + row) * NPIX + n0 + c4);
    st[row][c4 + 0] = (bf16_t)v.x; st[row][c4 + 1] = (bf16_t)v.y;
    st[row][c4 + 2] = (bf16_t)v.z; st[row][c4 + 3] = (bf16_t)v.w;
  }
  __syncthreads();
  bf16_t* Xit = (bf16_t*)(ws + OFF_XIT) + (size_t)b * NPIX * CCH;
  const int nr = t >> 2, cc = (t & 3) * 16;
  bf16x8 o0, o1;
#pragma unroll
  for (int j = 0; j < 8; ++j) o0[j] = st[cc + j][nr];
#pragma unroll
  for (int j = 0; j < 8; ++j) o1[j] = st[cc + 8 + j][nr];
  *(bf16x8*)(Xit + (size_t)(n0 + nr) * CCH + c0 + cc) = o0;
  *(bf16x8*)(Xit + (size_t)(n0 + nr) * CCH + c0 + cc + 8) = o1;
}

__device__ void gram_body(int bx, int b, const float* __restrict__ xj,
                          float* __restrict__ ws, unsigned char* SMEM) {
  const int ks = bx & 15;
  const int tl = bx >> 4;                 // 0:(0,0) 1:(0,1) 2:(1,1)
  const int i0 = (tl == 2) ? 128 : 0;
  const int j0 = (tl == 0) ? 0 : 128;
  const float* __restrict__ X = xj + (size_t)b * CCH * NPIX;
  bf16_t (*sA)[128][40] = (bf16_t(*)[128][40])SMEM;            // [2][128][40]
  bf16_t (*sB)[128][40] = (bf16_t(*)[128][40])(SMEM + 20480);  // [2][128][40]
  const int t = threadIdx.x;
  const int w = t >> 6, lane = t & 63;
  const f32x4 z4 = {0.f, 0.f, 0.f, 0.f};
  f32x4 acc[2][8];
#pragma unroll
  for (int fr = 0; fr < 2; ++fr)
#pragma unroll
    for (int fc = 0; fc < 8; ++fc) acc[fr][fc] = z4;
  float rsum = 0.f;
  const int k0 = ks * 256;
  const int srow = t >> 1, sh16 = (t & 1) * 16;
  const bool haveB = (tl == 1);

  float4 a0, a1, a2, a3, b0, b1, b2, b3;
  auto LOAD = [&](int kc) {
    const float* pa = X + (size_t)(i0 + srow) * NPIX + k0 + kc + sh16;
    ld4(pa, a0, a1, a2, a3);
    rsum += a0.x + a0.y + a0.z + a0.w + a1.x + a1.y + a1.z + a1.w
          + a2.x + a2.y + a2.z + a2.w + a3.x + a3.y + a3.z + a3.w;
    if (haveB) {
      const float* pb = X + (size_t)(j0 + srow) * NPIX + k0 + kc + sh16;
      ld4(pb, b0, b1, b2, b3);
    }
  };
  auto WRITE = [&](int q) {
    bf16x8 u0, u1;
    pack8(a0, a1, u0); pack8(a2, a3, u1);
    *(bf16x8*)&sA[q][srow][sh16] = u0;
    *(bf16x8*)&sA[q][srow][sh16 + 8] = u1;
    if (haveB) {
      bf16x8 w0, w1;
      pack8(b0, b1, w0); pack8(b2, b3, w1);
      *(bf16x8*)&sB[q][srow][sh16] = w0;
      *(bf16x8*)&sB[q][srow][sh16 + 8] = w1;
    }
  };

  LOAD(0);
  WRITE(0);
  __syncthreads();
  int cur = 0;
  for (int kc8 = 0; kc8 < 8; ++kc8) {
    if (kc8 < 7) LOAD(32 * (kc8 + 1));
    const int fcol = 8 * (lane >> 4);
    const int lr = lane & 15;
    bf16_t (*SBc)[40] = haveB ? sB[cur] : sA[cur];
    const bf16x8 af0 = *(const bf16x8*)&sA[cur][32 * w + lr][fcol];
    const bf16x8 af1 = *(const bf16x8*)&sA[cur][32 * w + 16 + lr][fcol];
#pragma unroll
    for (int fc = 0; fc < 8; ++fc) {
      const bf16x8 bv = *(const bf16x8*)&SBc[16 * fc + lr][fcol];
      acc[0][fc] = __builtin_amdgcn_mfma_f32_16x16x32_bf16(af0, bv, acc[0][fc], 0, 0, 0);
      acc[1][fc] = __builtin_amdgcn_mfma_f32_16x16x32_bf16(af1, bv, acc[1][fc], 0, 0, 0);
    }
    if (kc8 < 7) WRITE(cur ^ 1);
    __syncthreads();
    cur ^= 1;
  }

  if (tl != 1) {
    const float o = __shfl_down(rsum, 1);
    if (!(t & 1)) ws[OFF_RSP + ((size_t)(b * 16 + ks)) * CCH + i0 + srow] = rsum + o;
  }
  float* GP = ws + OFF_GP + ((size_t)((b * 16 + ks) * 3 + tl)) * 16384;
  const int rbase = 32 * w + ((lane >> 4) << 2);
  const int col = lane & 15;
#pragma unroll
  for (int fr = 0; fr < 2; ++fr)
#pragma unroll
    for (int fc = 0; fc < 8; ++fc)
#pragma unroll
      for (int reg = 0; reg < 4; ++reg)
        GP[(size_t)(rbase + 16 * fr + reg) * 128 + 16 * fc + col] = acc[fr][fc][reg];
}

// ---------- mega: gram (x<48) | cvtT (48<=x<304) | pre (x>=304, y==0) ----------
__global__ __launch_bounds__(256) void k_mega(const float* __restrict__ xi,
                                              const float* __restrict__ xj,
                                              const float* __restrict__ Ww,
                                              const float* __restrict__ gw,
                                              const float* __restrict__ phw,
                                              const float* __restrict__ thw,
                                              const float* __restrict__ gb,
                                              const float* __restrict__ phb,
                                              const float* __restrict__ thb,
                                              float* __restrict__ ws) {
  __shared__ __align__(16) unsigned char SMEM[40960];
  const int bx = blockIdx.x, by = blockIdx.y;
  if (bx >= 304) {
    if (by == 0) pre_body(bx - 304, Ww, gw, phw, thw, gb, phb, thb, ws, SMEM);
    return;
  }
  if (bx >= 48) { cvtT_body(bx - 48, by, xi, ws, SMEM); return; }
  gram_body(bx, by, xj, ws, SMEM);
}

// ---------- reduce Gram partials + mirror + finalize rowsums ----------
__global__ __launch_bounds__(256) void k_greduce(float* __restrict__ ws) {
  const int b = blockIdx.y, i = blockIdx.x, j = threadIdx.x;
  const float* BP = ws + OFF_GP;
  const size_t base = (size_t)b * 48;
  int tl, idx;
  if (i < 128) {
    if (j < 128) { tl = 0; idx = i * 128 + j; }
    else         { tl = 1; idx = i * 128 + (j - 128); }
  } else {
    if (j < 128) { tl = 1; idx = j * 128 + (i - 128); }
    else         { tl = 2; idx = (i - 128) * 128 + (j - 128); }
  }
  float s = 0.f;
#pragma unroll 4
  for (int ks = 0; ks < 16; ++ks) s += BP[(base + ks * 3 + tl) * 16384 + idx];
  ws[OFF_G + (size_t)b * 65536 + i * CCH + j] = s;
  if (j < 16) {
    float v = ws[OFF_RSP + ((size_t)(b * 16 + j)) * CCH + i];
#pragma unroll
    for (int off = 8; off; off >>= 1) v += __shfl_down(v, off, 16);
    if (j == 0) ws[OFF_S + b * CCH + i] = v;
  }
}

// ---------- K = A @ G (and u = A @ s) ----------
__global__ __launch_bounds__(256) void k_kmat(float* __restrict__ ws) {
  const int b = blockIdx.y;
  const int i0 = (blockIdx.x >> 2) * 64, j0 = (blockIdx.x & 3) * 64;
  const int t = threadIdx.x;
  const float* A = ws + OFF_A;
  const float* G = ws + OFF_G + (size_t)b * 65536;
  __shared__ float s1[64][65];
  __shared__ float s2[64][65];
  if (j0 == 0 && t < 64) {
    const float* sv = ws + OFF_S + b * CCH;
    float s = 0.f;
    for (int k = 0; k < 256; ++k) s += A[(i0 + t) * CCH + k] * sv[k];
    ws[OFF_U + b * CCH + i0 + t] = s;
  }
  float acc[4][4] = {};
  mm64_compute<false>(A, G, i0, j0, acc, s1, s2);
  float* K = ws + OFF_K + (size_t)b * 65536;
  const int tx = t & 15, ty = t >> 4;
#pragma unroll
  for (int i = 0; i < 4; ++i) {
    const float4 v = make_float4(acc[i][0], acc[i][1], acc[i][2], acc[i][3]);
    *(float4*)(K + (size_t)(i0 + 4 * ty + i) * CCH + j0 + 4 * tx) = v;
  }
}

// ---------- M' = (1/N)(K Bm + u r^T + w1 v^T) + w1 r^T + I (bf16) ; e ----------
__global__ __launch_bounds__(256) void k_mmat(const float* __restrict__ Wb, float* __restrict__ ws) {
  const int b = blockIdx.y;
  const int i0 = (blockIdx.x >> 2) * 64, j0 = (blockIdx.x & 3) * 64;
  const int t = threadIdx.x;
  const float* Kb = ws + OFF_K + (size_t)b * 65536;
  const float* Bm = ws + OFF_BM;
  const float* sv = ws + OFF_S + b * CCH;
  __shared__ float s1[64][65];
  __shared__ float s2[64][65];
  __shared__ float vs[64];
  __shared__ float red[256];
  __shared__ float sdt_s;
  red[t] = sv[t] * ws[OFF_T1 + t];
  __syncthreads();
  for (int off = 128; off; off >>= 1) { if (t < off) red[t] += red[t + off]; __syncthreads(); }
  if (t == 0) sdt_s = red[0];
  if (t < 64) {
    float s = 0.f;
    for (int k = 0; k < 256; ++k) s += Bm[k * CCH + j0 + t] * sv[k];
    vs[t] = s;
  }
  __syncthreads();
  float acc[4][4] = {};
  mm64_compute<false>(Kb, Bm, i0, j0, acc, s1, s2);
  const float c1 = ws[OFF_C1];
  const float sdt = sdt_s;
  const int tx = t & 15, ty = t >> 4;
  bf16_t* Mb = (bf16_t*)(ws + OFF_MP) + (size_t)b * 65536;
#pragma unroll
  for (int i = 0; i < 4; ++i) {
    const int gi = i0 + 4 * ty + i;
    const float ui = ws[OFF_U + b * CCH + gi];
    const float w1i = ws[OFF_W1 + gi];
    bf16x4 mv;
#pragma unroll
    for (int q = 0; q < 4; ++q) {
      const int gj = j0 + 4 * tx + q;
      const float rj = ws[OFF_R + gj];
      float v = (acc[i][q] + ui * rj + w1i * vs[4 * tx + q]) * INVN + w1i * rj;
      if (gi == gj) v += 1.0f;
      mv[q] = (bf16_t)v;
    }
    *(bf16x4*)&Mb[(size_t)gi * CCH + j0 + 4 * tx] = mv;
  }
  if (j0 == 0 && t < 64) {
    const int gi = i0 + t;
    float s = 0.f;
    for (int k = 0; k < 256; ++k) s += Kb[gi * CCH + k] * ws[OFF_T1 + k];
    const float ui = ws[OFF_U + b * CCH + gi], w1i = ws[OFF_W1 + gi];
    ws[OFF_E + b * CCH + gi] = INVN * (s + c1 * ui + sdt * w1i) + c1 * w1i + Wb[gi];
  }
}

// ---------- Z^T 64-n tiles via MFMA, double-buffered. APPLY=0: BN partials; 1: write out ----------
template <int APPLY>
__global__ __launch_bounds__(256) void k_zmm(float* __restrict__ ws, float* __restrict__ out) {
  const int b = blockIdx.y, nblk = blockIdx.x;      // 64 nblks of 64
  const int n0 = nblk * 64;
  const int t = threadIdx.x;
  const int w = t >> 6, lane = t & 63;
  const int rg = w >> 1, cg = w & 1;
  __shared__ __align__(16) bf16_t sA[2][64][40];
  __shared__ __align__(16) bf16_t sB[2][256][40];
  __shared__ float sC1[256], sC2[256];
  __shared__ float redS[4][128], redQ[4][128];
  {
    const float e = ws[OFF_E + b * CCH + t];
    if (APPLY) {
      const float sc = ws[OFF_SCALE + t];
      sC1[t] = sc;
      sC2[t] = e * sc + ws[OFF_SHIFT + t];
    } else {
      sC1[t] = e;
    }
  }
  const bf16_t* Xit = (const bf16_t*)(ws + OFF_XIT) + (size_t)b * NPIX * CCH;
  const bf16_t* Mp = (const bf16_t*)(ws + OFF_MP) + (size_t)b * 65536;
  const f32x4 z4 = {0.f, 0.f, 0.f, 0.f};
  f32x4 acc[2][8];
#pragma unroll
  for (int fr = 0; fr < 2; ++fr)
#pragma unroll
    for (int fc = 0; fc < 8; ++fc) acc[fr][fc] = z4;
  const int arow = t >> 2, achk = (t & 3) * 8;      // 64 rows x 32 k
  bf16x8 ra, rb0, rb1, rb2, rb3;
  ra  = *(const bf16x8*)(Xit + (size_t)(n0 + arow) * CCH + achk);
  rb0 = *(const bf16x8*)(Mp + (size_t)(arow)       * CCH + achk);
  rb1 = *(const bf16x8*)(Mp + (size_t)(64 + arow)  * CCH + achk);
  rb2 = *(const bf16x8*)(Mp + (size_t)(128 + arow) * CCH + achk);
  rb3 = *(const bf16x8*)(Mp + (size_t)(192 + arow) * CCH + achk);
  *(bf16x8*)&sA[0][arow][achk] = ra;
  *(bf16x8*)&sB[0][arow][achk] = rb0;
  *(bf16x8*)&sB[0][64 + arow][achk] = rb1;
  *(bf16x8*)&sB[0][128 + arow][achk] = rb2;
  *(bf16x8*)&sB[0][192 + arow][achk] = rb3;
  __syncthreads();
  int cur = 0;
  for (int ks = 0; ks < 8; ++ks) {
    const int nk = 32 * (ks + 1);
    if (ks < 7) {
      ra  = *(const bf16x8*)(Xit + (size_t)(n0 + arow) * CCH + nk + achk);
      rb0 = *(const bf16x8*)(Mp + (size_t)(arow)       * CCH + nk + achk);
      rb1 = *(const bf16x8*)(Mp + (size_t)(64 + arow)  * CCH + nk + achk);
      rb2 = *(const bf16x8*)(Mp + (size_t)(128 + arow) * CCH + nk + achk);
      rb3 = *(const bf16x8*)(Mp + (size_t)(192 + arow) * CCH + nk + achk);
    }
    const int fcol = 8 * (lane >> 4);
    const int lr = lane & 15;
    const bf16x8 af0 = *(const bf16x8*)&sA[cur][32 * rg + lr][fcol];
    const bf16x8 af1 = *(const bf16x8*)&sA[cur][32 * rg + 16 + lr][fcol];
#pragma unroll
    for (int fc = 0; fc < 8; ++fc) {
      const bf16x8 bv = *(const bf16x8*)&sB[cur][128 * cg + 16 * fc + lr][fcol];
      acc[0][fc] = __builtin_amdgcn_mfma_f32_16x16x32_bf16(af0, bv, acc[0][fc], 0, 0, 0);
      acc[1][fc] = __builtin_amdgcn_mfma_f32_16x16x32_bf16(af1, bv, acc[1][fc], 0, 0, 0);
    }
    if (ks < 7) {
      *(bf16x8*)&sA[cur ^ 1][arow][achk] = ra;
      *(bf16x8*)&sB[cur ^ 1][arow][achk] = rb0;
      *(bf16x8*)&sB[cur ^ 1][64 + arow][achk] = rb1;
      *(bf16x8*)&sB[cur ^ 1][128 + arow][achk] = rb2;
      *(bf16x8*)&sB[cur ^ 1][192 + arow][achk] = rb3;
    }
    __syncthreads();
    cur ^= 1;
  }
  if (APPLY) {
#pragma unroll
    for (int fc = 0; fc < 8; ++fc) {
      const int c = 128 * cg + 16 * fc + (lane & 15);
      const float sc = sC1[c], b2 = sC2[c];
      float* op = out + ((size_t)b * CCH + c) * NPIX + n0 + 32 * rg + ((lane >> 4) << 2);
#pragma unroll
      for (int fr = 0; fr < 2; ++fr) {
        float4 v;
        v.x = acc[fr][fc][0] * sc + b2;
        v.y = acc[fr][fc][1] * sc + b2;
        v.z = acc[fr][fc][2] * sc + b2;
        v.w = acc[fr][fc][3] * sc + b2;
        *(float4*)(op + 16 * fr) = v;
      }
    }
  } else {
    float ps[8], pq[8];
#pragma unroll
    for (int fc = 0; fc < 8; ++fc) {
      const int c = 128 * cg + 16 * fc + (lane & 15);
      const float e = sC1[c];
      float s = 0.f, q = 0.f;
#pragma unroll
      for (int fr = 0; fr < 2; ++fr)
#pragma unroll
        for (int reg = 0; reg < 4; ++reg) {
          const float z = acc[fr][fc][reg] + e;
          s += z; q += z * z;
        }
      s += __shfl_xor(s, 16); s += __shfl_xor(s, 32);
      q += __shfl_xor(q, 16); q += __shfl_xor(q, 32);
      ps[fc] = s; pq[fc] = q;
    }
    if (lane < 16) {
#pragma unroll
      for (int fc = 0; fc < 8; ++fc) {
        redS[w][16 * fc + lane] = ps[fc];
        redQ[w][16 * fc + lane] = pq[fc];
      }
    }
    __syncthreads();
    if (t < 256) {
      const int cg2 = t >> 7, c = t & 127;
      float s = 0.f, q = 0.f;
#pragma unroll
      for (int rg2 = 0; rg2 < 2; ++rg2) {
        s += redS[rg2 * 2 + cg2][c];
        q += redQ[rg2 * 2 + cg2][c];
      }
      ws[OFF_ZPS + ((size_t)(b * 64 + nblk)) * CCH + (cg2 << 7) + c] = s;
      ws[OFF_ZPQ + ((size_t)(b * 64 + nblk)) * CCH + (cg2 << 7) + c] = q;
    }
  }
}

// ---------- BN stats -> scale/shift ----------
__global__ __launch_bounds__(256) void k_bnstats(const float* __restrict__ gamma,
                                                 const float* __restrict__ beta,
                                                 float* __restrict__ ws) {
  const int c = threadIdx.x;
  float s = 0.f, q = 0.f;
  for (int e = 0; e < 512; ++e) {
    s += ws[OFF_ZPS + (size_t)e * CCH + c];
    q += ws[OFF_ZPQ + (size_t)e * CCH + c];
  }
  const float mean = s * INVCNT;
  const float var = q * INVCNT - mean * mean;
  const float sc = gamma[c] * rsqrtf(var + 1e-5f);
  ws[OFF_SCALE + c] = sc;
  ws[OFF_SHIFT + c] = beta[c] - mean * sc;
}

extern "C" void kernel_launch(void* const* d_in, const int* in_sizes, int n_in,
                              void* d_out, int out_size, void* d_ws, size_t ws_size,
                              hipStream_t stream) {
  const float* xi  = (const float*)d_in[0];
  const float* xj  = (const float*)d_in[1];
  const float* gw  = (const float*)d_in[2];
  const float* gb  = (const float*)d_in[3];
  const float* thw = (const float*)d_in[4];
  const float* thb = (const float*)d_in[5];
  const float* phw = (const float*)d_in[6];
  const float* phb = (const float*)d_in[7];
  const float* Ww  = (const float*)d_in[8];
  const float* Wb  = (const float*)d_in[9];
  const float* gamma = (const float*)d_in[10];
  const float* beta  = (const float*)d_in[11];
  float* ws = (float*)d_ws;
  float* out = (float*)d_out;

  k_mega<<<dim3(337, 8), 256, 0, stream>>>(xi, xj, Ww, gw, phw, thw, gb, phb, thb, ws);
  k_greduce<<<dim3(256, 8), 256, 0, stream>>>(ws);
  k_kmat<<<dim3(16, 8), 256, 0, stream>>>(ws);
  k_mmat<<<dim3(16, 8), 256, 0, stream>>>(Wb, ws);
  k_zmm<0><<<dim3(64, 8), 256, 0, stream>>>(ws, out);
  k_bnstats<<<1, 256, 0, stream>>>(gamma, beta, ws);
  k_zmm<1><<<dim3(64, 8), 256, 0, stream>>>(ws, out);
}

// Round 5
// 98.828 us; speedup vs baseline: 2.7276x; 1.7287x over previous
//
#include <hip/hip_runtime.h>
#include <cstddef>

#define CCH 256
#define NPIX 4096
#define NB 8
#define INVCNT (1.0f/32768.0f)
#define INVN (1.0f/4096.0f)

typedef __bf16 bf16_t;
typedef __attribute__((ext_vector_type(8))) __bf16 bf16x8;
typedef __attribute__((ext_vector_type(4))) __bf16 bf16x4;
typedef __attribute__((ext_vector_type(4))) float f32x4;

// ---- workspace layout (float offsets) ----
#define OFF_S      0u          // 8*256 rowsums of Xj
#define OFF_AB     2048u       // A = Ww@gw  bf16 [256][256] (32768 floats)
#define OFF_BMT    34816u      // BmT = thw^T@phw bf16 [256][256] (32768 floats)
#define OFF_T1     67584u
#define OFF_R      67840u
#define OFF_W1     68096u
#define OFF_C1     68352u
#define OFF_G      68608u      // G fp32 8 x 256x256 (524288)
#define OFF_MP     592896u     // M' bf16 8x65536 el (262144 floats)
#define OFF_E      855040u     // e 8x256
#define OFF_RSP    857088u     // rowsum partials 8x16x256 (32768)
#define OFF_ZPS    889856u     // bn partial sums  [c 256][entry 512]
#define OFF_ZPQ    1020928u    // bn partial sumsq [c 256][entry 512]
#define OFF_SCALE  1152000u
#define OFF_SHIFT  1152256u
#define OFF_GP     1152512u    // Gram partials fp32 8*16*3*16384 (6291456)
#define OFF_XIT    7443968u    // Xi_t bf16 8*4096*256 (4194304 floats)

__device__ __forceinline__ void pack8(const float4& x, const float4& y, bf16x8& o) {
  o[0]=(bf16_t)x.x; o[1]=(bf16_t)x.y; o[2]=(bf16_t)x.z; o[3]=(bf16_t)x.w;
  o[4]=(bf16_t)y.x; o[5]=(bf16_t)y.y; o[6]=(bf16_t)y.z; o[7]=(bf16_t)y.w;
}

__device__ __forceinline__ void ld4(const float* p, float4& a0, float4& a1, float4& a2, float4& a3) {
  a0 = *(const float4*)p;       a1 = *(const float4*)(p + 4);
  a2 = *(const float4*)(p + 8); a3 = *(const float4*)(p + 12);
}

// ---------- generic 64x64-tile NN/TN fp32 matmul over K=256 ----------
template <bool ATRANS>
__device__ __forceinline__ void mm64_compute(const float* __restrict__ A,
                                             const float* __restrict__ B,
                                             int i0, int j0,
                                             float (&acc)[4][4],
                                             float (*s1)[65], float (*s2)[65]) {
  const int t = threadIdx.x, tx = t & 15, ty = t >> 4;
  for (int k0 = 0; k0 < 256; k0 += 64) {
#pragma unroll
    for (int it = 0; it < 4; ++it) {
      const int f = t + 256 * it;
      const int row = f >> 4, cc = (f & 15) * 4;
      float4 va;
      if (ATRANS)
        va = *(const float4*)(A + (size_t)(k0 + row) * CCH + i0 + cc);
      else
        va = *(const float4*)(A + (size_t)(i0 + row) * CCH + k0 + cc);
      const float4 vb = *(const float4*)(B + (size_t)(k0 + row) * CCH + j0 + cc);
      s1[row][cc + 0] = va.x; s1[row][cc + 1] = va.y; s1[row][cc + 2] = va.z; s1[row][cc + 3] = va.w;
      s2[row][cc + 0] = vb.x; s2[row][cc + 1] = vb.y; s2[row][cc + 2] = vb.z; s2[row][cc + 3] = vb.w;
    }
    __syncthreads();
#pragma unroll 4
    for (int kk = 0; kk < 64; ++kk) {
      float ar[4], br[4];
#pragma unroll
      for (int i = 0; i < 4; ++i) ar[i] = ATRANS ? s1[kk][4 * ty + i] : s1[4 * ty + i][kk];
#pragma unroll
      for (int j = 0; j < 4; ++j) br[j] = s2[kk][4 * tx + j];
#pragma unroll
      for (int i = 0; i < 4; ++i)
#pragma unroll
        for (int j = 0; j < 4; ++j) acc[i][j] += ar[i] * br[j];
    }
    __syncthreads();
  }
}

// ---------- mega-kernel bodies ----------
__device__ void pre_body(int blk, const float* Ww, const float* gw, const float* phw,
                         const float* thw, const float* gb, const float* phb,
                         const float* thb, float* ws, unsigned char* SMEM) {
  const int t = threadIdx.x;
  if (blk < 32) {
    float (*s1)[65] = (float(*)[65])SMEM;
    float (*s2)[65] = (float(*)[65])(SMEM + 16640);
    const int tb = blk & 15;
    const int i0 = (tb >> 2) * 64, j0 = (tb & 3) * 64;
    float acc[4][4] = {};
    if (blk < 16) mm64_compute<false>(Ww, gw, i0, j0, acc, s1, s2);   // A = Ww@gw
    else          mm64_compute<true >(thw, phw, i0, j0, acc, s1, s2); // BmT = thw^T@phw
    bf16_t* outp = (bf16_t*)(ws + (blk < 16 ? OFF_AB : OFF_BMT));
    const int tx = t & 15, ty = t >> 4;
#pragma unroll
    for (int i = 0; i < 4; ++i) {
      bf16x4 mv;
#pragma unroll
      for (int q = 0; q < 4; ++q) mv[q] = (bf16_t)acc[i][q];
      *(bf16x4*)&outp[(size_t)(i0 + 4 * ty + i) * CCH + j0 + 4 * tx] = mv;
    }
  } else {
    float t1v = 0.f, rv = 0.f, w1v = 0.f;
    for (int k = 0; k < 256; ++k) {
      t1v += phw[k * CCH + t] * thb[k];
      rv  += thw[k * CCH + t] * phb[k];
      w1v += Ww[t * CCH + k] * gb[k];
    }
    ws[OFF_T1 + t] = t1v; ws[OFF_R + t] = rv; ws[OFF_W1 + t] = w1v;
    float* red = (float*)SMEM;
    red[t] = phb[t] * thb[t];
    __syncthreads();
    for (int off = 128; off; off >>= 1) { if (t < off) red[t] += red[t + off]; __syncthreads(); }
    if (t == 0) ws[OFF_C1] = red[0];
  }
}

__device__ void cvtT_body(int bx, int b, const float* __restrict__ xi,
                          float* __restrict__ ws, unsigned char* SMEM) {
  bf16_t (*st)[72] = (bf16_t(*)[72])SMEM;
  const int c0 = (bx & 3) * 64;
  const int n0 = (bx >> 2) * 64;
  const float* X = xi + (size_t)b * CCH * NPIX;
  const int t = threadIdx.x;
  const int r = t >> 4, c4 = (t & 15) * 4;
#pragma unroll
  for (int it = 0; it < 4; ++it) {
    const int row = r + 16 * it;
    const float4 v = *(const float4*)(X + (size_t)(c0 + row) * NPIX + n0 + c4);
    st[row][c4 + 0] = (bf16_t)v.x; st[row][c4 + 1] = (bf16_t)v.y;
    st[row][c4 + 2] = (bf16_t)v.z; st[row][c4 + 3] = (bf16_t)v.w;
  }
  __syncthreads();
  bf16_t* Xit = (bf16_t*)(ws + OFF_XIT) + (size_t)b * NPIX * CCH;
  const int nr = t >> 2, cc = (t & 3) * 16;
  bf16x8 o0, o1;
#pragma unroll
  for (int j = 0; j < 8; ++j) o0[j] = st[cc + j][nr];
#pragma unroll
  for (int j = 0; j < 8; ++j) o1[j] = st[cc + 8 + j][nr];
  *(bf16x8*)(Xit + (size_t)(n0 + nr) * CCH + c0 + cc) = o0;
  *(bf16x8*)(Xit + (size_t)(n0 + nr) * CCH + c0 + cc + 8) = o1;
}

__device__ void gram_body(int bx, int b, const float* __restrict__ xj,
                          float* __restrict__ ws, unsigned char* SMEM) {
  const int ks = bx & 15;
  const int tl = bx >> 4;                 // 0:(0,0) 1:(0,1) 2:(1,1)
  const int i0 = (tl == 2) ? 128 : 0;
  const int j0 = (tl == 0) ? 0 : 128;
  const float* __restrict__ X = xj + (size_t)b * CCH * NPIX;
  bf16_t (*sA)[128][40] = (bf16_t(*)[128][40])SMEM;            // [2][128][40]
  bf16_t (*sB)[128][40] = (bf16_t(*)[128][40])(SMEM + 20480);  // [2][128][40]
  const int t = threadIdx.x;
  const int w = t >> 6, lane = t & 63;
  const f32x4 z4 = {0.f, 0.f, 0.f, 0.f};
  f32x4 acc[2][8];
#pragma unroll
  for (int fr = 0; fr < 2; ++fr)
#pragma unroll
    for (int fc = 0; fc < 8; ++fc) acc[fr][fc] = z4;
  float rsum = 0.f;
  const int k0 = ks * 256;
  const int srow = t >> 1, sh16 = (t & 1) * 16;
  const bool haveB = (tl == 1);

  float4 a0, a1, a2, a3, b0, b1, b2, b3;
  auto LOAD = [&](int kc) {
    const float* pa = X + (size_t)(i0 + srow) * NPIX + k0 + kc + sh16;
    ld4(pa, a0, a1, a2, a3);
    rsum += a0.x + a0.y + a0.z + a0.w + a1.x + a1.y + a1.z + a1.w
          + a2.x + a2.y + a2.z + a2.w + a3.x + a3.y + a3.z + a3.w;
    if (haveB) {
      const float* pb = X + (size_t)(j0 + srow) * NPIX + k0 + kc + sh16;
      ld4(pb, b0, b1, b2, b3);
    }
  };
  auto WRITE = [&](int q) {
    bf16x8 u0, u1;
    pack8(a0, a1, u0); pack8(a2, a3, u1);
    *(bf16x8*)&sA[q][srow][sh16] = u0;
    *(bf16x8*)&sA[q][srow][sh16 + 8] = u1;
    if (haveB) {
      bf16x8 w0, w1;
      pack8(b0, b1, w0); pack8(b2, b3, w1);
      *(bf16x8*)&sB[q][srow][sh16] = w0;
      *(bf16x8*)&sB[q][srow][sh16 + 8] = w1;
    }
  };

  LOAD(0);
  WRITE(0);
  __syncthreads();
  int cur = 0;
  for (int kc8 = 0; kc8 < 8; ++kc8) {
    if (kc8 < 7) LOAD(32 * (kc8 + 1));
    const int fcol = 8 * (lane >> 4);
    const int lr = lane & 15;
    bf16_t (*SBc)[40] = haveB ? sB[cur] : sA[cur];
    const bf16x8 af0 = *(const bf16x8*)&sA[cur][32 * w + lr][fcol];
    const bf16x8 af1 = *(const bf16x8*)&sA[cur][32 * w + 16 + lr][fcol];
#pragma unroll
    for (int fc = 0; fc < 8; ++fc) {
      const bf16x8 bv = *(const bf16x8*)&SBc[16 * fc + lr][fcol];
      acc[0][fc] = __builtin_amdgcn_mfma_f32_16x16x32_bf16(af0, bv, acc[0][fc], 0, 0, 0);
      acc[1][fc] = __builtin_amdgcn_mfma_f32_16x16x32_bf16(af1, bv, acc[1][fc], 0, 0, 0);
    }
    if (kc8 < 7) WRITE(cur ^ 1);
    __syncthreads();
    cur ^= 1;
  }

  if (tl != 1) {
    const float o = __shfl_down(rsum, 1);
    if (!(t & 1)) ws[OFF_RSP + ((size_t)(b * 16 + ks)) * CCH + i0 + srow] = rsum + o;
  }
  float* GP = ws + OFF_GP + ((size_t)((b * 16 + ks) * 3 + tl)) * 16384;
  const int rbase = 32 * w + ((lane >> 4) << 2);
  const int col = lane & 15;
#pragma unroll
  for (int fr = 0; fr < 2; ++fr)
#pragma unroll
    for (int fc = 0; fc < 8; ++fc)
#pragma unroll
      for (int reg = 0; reg < 4; ++reg)
        GP[(size_t)(rbase + 16 * fr + reg) * 128 + 16 * fc + col] = acc[fr][fc][reg];
}

// ---------- mega: gram (x<48) | cvtT (48<=x<304) | pre (x>=304, y==0) ----------
__global__ __launch_bounds__(256) void k_mega(const float* __restrict__ xi,
                                              const float* __restrict__ xj,
                                              const float* __restrict__ Ww,
                                              const float* __restrict__ gw,
                                              const float* __restrict__ phw,
                                              const float* __restrict__ thw,
                                              const float* __restrict__ gb,
                                              const float* __restrict__ phb,
                                              const float* __restrict__ thb,
                                              float* __restrict__ ws) {
  __shared__ __align__(16) unsigned char SMEM[40960];
  const int bx = blockIdx.x, by = blockIdx.y;
  if (bx >= 304) {
    if (by == 0) pre_body(bx - 304, Ww, gw, phw, thw, gb, phb, thb, ws, SMEM);
    return;
  }
  if (bx >= 48) { cvtT_body(bx - 48, by, xi, ws, SMEM); return; }
  gram_body(bx, by, xj, ws, SMEM);
}

// ---------- reduce Gram partials (coalesced) + mirror + finalize rowsums ----------
__global__ __launch_bounds__(256) void k_greduce(float* __restrict__ ws) {
  const int b = blockIdx.y, bx = blockIdx.x, t = threadIdx.x;
  const float* BP = ws + OFF_GP + (size_t)b * 48 * 16384;
  float* G = ws + OFF_G + (size_t)b * 65536;
  if (bx < 128) {
    const int i = bx;
    const int j = t;
    const int tl = (j < 128) ? 0 : 1;
    const size_t idx = (size_t)i * 128 + (j & 127);
    float s = 0.f;
#pragma unroll 4
    for (int ks = 0; ks < 16; ++ks) s += BP[((size_t)ks * 3 + tl) * 16384 + idx];
    G[(size_t)i * CCH + j] = s;
    if (j >= 128) G[(size_t)j * CCH + i] = s;    // symmetric mirror
    if (t < 32) {
      const int row = (t < 16) ? i : (i + 128);
      const int l = t & 15;
      float v = ws[OFF_RSP + ((size_t)(b * 16 + l)) * CCH + row];
#pragma unroll
      for (int off = 8; off; off >>= 1) v += __shfl_down(v, off, 16);
      if (l == 0) ws[OFF_S + b * CCH + row] = v;
    }
  } else {
    const int r = 128 + ((bx - 128) << 1) + (t >> 7);
    const int j = 128 + (t & 127);
    const size_t idx = (size_t)(r - 128) * 128 + (j - 128);
    float s = 0.f;
#pragma unroll 4
    for (int ks = 0; ks < 16; ++ks) s += BP[((size_t)ks * 3 + 2) * 16384 + idx];
    G[(size_t)r * CCH + j] = s;
  }
}

// ---------- fused K = A@G (MFMA), e, M' = f(K@BmT^T) (MFMA) ----------
__global__ __launch_bounds__(256) void k_kmmat(const float* __restrict__ Wb, float* __restrict__ ws) {
  const int b = blockIdx.y;
  const int i0 = blockIdx.x * 64;
  const int t = threadIdx.x;
  const int w = t >> 6, lane = t & 63;
  const int rg = w >> 1, cg = w & 1;
  const int lr = lane & 15, hi = lane >> 4;
  const int fcol = 8 * hi;

  __shared__ __align__(16) bf16_t sA[2][64][40];
  __shared__ __align__(16) bf16_t sB[2][256][40];
  __shared__ __align__(16) bf16_t sK[64][264];
  __shared__ float sS[256], sT1[256], sR[256], sW1[256], sVS[256];
  __shared__ float sU[64];
  __shared__ float red[256];
  __shared__ float sdt_sh;

  const bf16_t* Ab  = (const bf16_t*)(ws + OFF_AB);
  const bf16_t* BmT = (const bf16_t*)(ws + OFF_BMT);
  const float*  Gf  = ws + OFF_G + (size_t)b * 65536;

  sS[t]  = ws[OFF_S + b * CCH + t];
  sT1[t] = ws[OFF_T1 + t];
  sR[t]  = ws[OFF_R + t];
  sW1[t] = ws[OFF_W1 + t];
  __syncthreads();
  red[t] = sS[t] * sT1[t];
  __syncthreads();
  for (int off = 128; off; off >>= 1) { if (t < off) red[t] += red[t + off]; __syncthreads(); }
  if (t == 0) sdt_sh = red[0];
  {
    float a = 0.f;
    for (int k8 = 0; k8 < 256; k8 += 8) {
      const bf16x8 v = *(const bf16x8*)&BmT[(size_t)t * CCH + k8];
#pragma unroll
      for (int q = 0; q < 8; ++q) a += (float)v[q] * sS[k8 + q];
    }
    sVS[t] = a;
  }
  if (t < 64) {
    float a = 0.f;
    for (int k8 = 0; k8 < 256; k8 += 8) {
      const bf16x8 v = *(const bf16x8*)&Ab[(size_t)(i0 + t) * CCH + k8];
#pragma unroll
      for (int q = 0; q < 8; ++q) a += (float)v[q] * sS[k8 + q];
    }
    sU[t] = a;
  }

  const f32x4 z4 = {0.f, 0.f, 0.f, 0.f};
  const int arow = t >> 2, achk = (t & 3) * 8;

  // ---- phase B: K = A @ G (G symmetric -> A.G^T pattern) ----
  f32x4 acc[2][8];
#pragma unroll
  for (int fr = 0; fr < 2; ++fr)
#pragma unroll
    for (int fc = 0; fc < 8; ++fc) acc[fr][fc] = z4;
  bf16x8 ra;
  float4 g[4][2];
  auto LOADB = [&](int k) {
    ra = *(const bf16x8*)&Ab[(size_t)(i0 + arow) * CCH + k + achk];
#pragma unroll
    for (int h = 0; h < 4; ++h) {
      const float* p = &Gf[(size_t)(64 * h + arow) * CCH + k + achk];
      g[h][0] = *(const float4*)p;
      g[h][1] = *(const float4*)(p + 4);
    }
  };
  auto WRITEB = [&](int q) {
    *(bf16x8*)&sA[q][arow][achk] = ra;
#pragma unroll
    for (int h = 0; h < 4; ++h) {
      bf16x8 u;
      pack8(g[h][0], g[h][1], u);
      *(bf16x8*)&sB[q][64 * h + arow][achk] = u;
    }
  };
  LOADB(0);
  WRITEB(0);
  __syncthreads();
  int cur = 0;
  for (int ks = 0; ks < 8; ++ks) {
    if (ks < 7) LOADB(32 * (ks + 1));
    const bf16x8 af0 = *(const bf16x8*)&sA[cur][32 * rg + lr][fcol];
    const bf16x8 af1 = *(const bf16x8*)&sA[cur][32 * rg + 16 + lr][fcol];
#pragma unroll
    for (int fc = 0; fc < 8; ++fc) {
      const bf16x8 bv = *(const bf16x8*)&sB[cur][128 * cg + 16 * fc + lr][fcol];
      acc[0][fc] = __builtin_amdgcn_mfma_f32_16x16x32_bf16(af0, bv, acc[0][fc], 0, 0, 0);
      acc[1][fc] = __builtin_amdgcn_mfma_f32_16x16x32_bf16(af1, bv, acc[1][fc], 0, 0, 0);
    }
    if (ks < 7) WRITEB(cur ^ 1);
    __syncthreads();
    cur ^= 1;
  }
  // K -> LDS bf16
#pragma unroll
  for (int fr = 0; fr < 2; ++fr)
#pragma unroll
    for (int fc = 0; fc < 8; ++fc)
#pragma unroll
      for (int reg = 0; reg < 4; ++reg)
        sK[32 * rg + 16 * fr + 4 * hi + reg][128 * cg + 16 * fc + lr] = (bf16_t)acc[fr][fc][reg];
  __syncthreads();

  // e (t<64): needs K row dot t1
  if (t < 64) {
    float dot = 0.f;
    for (int k8 = 0; k8 < 256; k8 += 8) {
      const bf16x8 v = *(const bf16x8*)&sK[t][k8];
#pragma unroll
      for (int q = 0; q < 8; ++q) dot += (float)v[q] * sT1[k8 + q];
    }
    const float c1 = ws[OFF_C1];
    const float ui = sU[t], w1i = sW1[i0 + t];
    ws[OFF_E + b * CCH + i0 + t] = INVN * (dot + c1 * ui + sdt_sh * w1i) + c1 * w1i + Wb[i0 + t];
  }

  // ---- phase C: Mcore = K @ Bm  (A-op = sK rows, B-op = BmT rows) ----
  f32x4 acc2[2][8];
#pragma unroll
  for (int fr = 0; fr < 2; ++fr)
#pragma unroll
    for (int fc = 0; fc < 8; ++fc) acc2[fr][fc] = z4;
  bf16x8 rb[4];
  auto LOADC = [&](int k) {
#pragma unroll
    for (int h = 0; h < 4; ++h)
      rb[h] = *(const bf16x8*)&BmT[(size_t)(64 * h + arow) * CCH + k + achk];
  };
  auto WRITEC = [&](int q) {
#pragma unroll
    for (int h = 0; h < 4; ++h)
      *(bf16x8*)&sB[q][64 * h + arow][achk] = rb[h];
  };
  LOADC(0);
  WRITEC(0);
  __syncthreads();
  cur = 0;
  for (int ks = 0; ks < 8; ++ks) {
    if (ks < 7) LOADC(32 * (ks + 1));
    const bf16x8 af0 = *(const bf16x8*)&sK[32 * rg + lr][32 * ks + fcol];
    const bf16x8 af1 = *(const bf16x8*)&sK[32 * rg + 16 + lr][32 * ks + fcol];
#pragma unroll
    for (int fc = 0; fc < 8; ++fc) {
      const bf16x8 bv = *(const bf16x8*)&sB[cur][128 * cg + 16 * fc + lr][fcol];
      acc2[0][fc] = __builtin_amdgcn_mfma_f32_16x16x32_bf16(af0, bv, acc2[0][fc], 0, 0, 0);
      acc2[1][fc] = __builtin_amdgcn_mfma_f32_16x16x32_bf16(af1, bv, acc2[1][fc], 0, 0, 0);
    }
    if (ks < 7) WRITEC(cur ^ 1);
    __syncthreads();
    cur ^= 1;
  }

  // epilogue: M' = (acc2 + u r^T + w1 vs^T)/N + w1 r^T + I  (bf16)
  bf16_t* Mp = (bf16_t*)(ws + OFF_MP) + (size_t)b * 65536;
#pragma unroll
  for (int fr = 0; fr < 2; ++fr)
#pragma unroll
    for (int fc = 0; fc < 8; ++fc) {
      const int j = 128 * cg + 16 * fc + lr;
      const float rj = sR[j], vsj = sVS[j];
#pragma unroll
      for (int reg = 0; reg < 4; ++reg) {
        const int il = 32 * rg + 16 * fr + 4 * hi + reg;
        const float ui = sU[il], w1i = sW1[i0 + il];
        float m = (acc2[fr][fc][reg] + ui * rj + w1i * vsj) * INVN + w1i * rj;
        if (i0 + il == j) m += 1.0f;
        Mp[(size_t)(i0 + il) * CCH + j] = (bf16_t)m;
      }
    }
}

// ---------- Z^T 64-n tiles via MFMA, double-buffered. APPLY=0: BN partials; 1: write out ----------
template <int APPLY>
__global__ __launch_bounds__(256) void k_zmm(float* __restrict__ ws, float* __restrict__ out) {
  const int b = blockIdx.y, nblk = blockIdx.x;      // 64 nblks of 64
  const int n0 = nblk * 64;
  const int t = threadIdx.x;
  const int w = t >> 6, lane = t & 63;
  const int rg = w >> 1, cg = w & 1;
  __shared__ __align__(16) bf16_t sA[2][64][40];
  __shared__ __align__(16) bf16_t sB[2][256][40];
  __shared__ float sC1[256], sC2[256];
  __shared__ float redS[4][128], redQ[4][128];
  {
    const float e = ws[OFF_E + b * CCH + t];
    if (APPLY) {
      const float sc = ws[OFF_SCALE + t];
      sC1[t] = sc;
      sC2[t] = e * sc + ws[OFF_SHIFT + t];
    } else {
      sC1[t] = e;
    }
  }
  const bf16_t* Xit = (const bf16_t*)(ws + OFF_XIT) + (size_t)b * NPIX * CCH;
  const bf16_t* Mp = (const bf16_t*)(ws + OFF_MP) + (size_t)b * 65536;
  const f32x4 z4 = {0.f, 0.f, 0.f, 0.f};
  f32x4 acc[2][8];
#pragma unroll
  for (int fr = 0; fr < 2; ++fr)
#pragma unroll
    for (int fc = 0; fc < 8; ++fc) acc[fr][fc] = z4;
  const int arow = t >> 2, achk = (t & 3) * 8;      // 64 rows x 32 k
  bf16x8 ra, rb0, rb1, rb2, rb3;
  ra  = *(const bf16x8*)(Xit + (size_t)(n0 + arow) * CCH + achk);
  rb0 = *(const bf16x8*)(Mp + (size_t)(arow)       * CCH + achk);
  rb1 = *(const bf16x8*)(Mp + (size_t)(64 + arow)  * CCH + achk);
  rb2 = *(const bf16x8*)(Mp + (size_t)(128 + arow) * CCH + achk);
  rb3 = *(const bf16x8*)(Mp + (size_t)(192 + arow) * CCH + achk);
  *(bf16x8*)&sA[0][arow][achk] = ra;
  *(bf16x8*)&sB[0][arow][achk] = rb0;
  *(bf16x8*)&sB[0][64 + arow][achk] = rb1;
  *(bf16x8*)&sB[0][128 + arow][achk] = rb2;
  *(bf16x8*)&sB[0][192 + arow][achk] = rb3;
  __syncthreads();
  int cur = 0;
  for (int ks = 0; ks < 8; ++ks) {
    const int nk = 32 * (ks + 1);
    if (ks < 7) {
      ra  = *(const bf16x8*)(Xit + (size_t)(n0 + arow) * CCH + nk + achk);
      rb0 = *(const bf16x8*)(Mp + (size_t)(arow)       * CCH + nk + achk);
      rb1 = *(const bf16x8*)(Mp + (size_t)(64 + arow)  * CCH + nk + achk);
      rb2 = *(const bf16x8*)(Mp + (size_t)(128 + arow) * CCH + nk + achk);
      rb3 = *(const bf16x8*)(Mp + (size_t)(192 + arow) * CCH + nk + achk);
    }
    const int fcol = 8 * (lane >> 4);
    const int lr = lane & 15;
    const bf16x8 af0 = *(const bf16x8*)&sA[cur][32 * rg + lr][fcol];
    const bf16x8 af1 = *(const bf16x8*)&sA[cur][32 * rg + 16 + lr][fcol];
#pragma unroll
    for (int fc = 0; fc < 8; ++fc) {
      const bf16x8 bv = *(const bf16x8*)&sB[cur][128 * cg + 16 * fc + lr][fcol];
      acc[0][fc] = __builtin_amdgcn_mfma_f32_16x16x32_bf16(af0, bv, acc[0][fc], 0, 0, 0);
      acc[1][fc] = __builtin_amdgcn_mfma_f32_16x16x32_bf16(af1, bv, acc[1][fc], 0, 0, 0);
    }
    if (ks < 7) {
      *(bf16x8*)&sA[cur ^ 1][arow][achk] = ra;
      *(bf16x8*)&sB[cur ^ 1][arow][achk] = rb0;
      *(bf16x8*)&sB[cur ^ 1][64 + arow][achk] = rb1;
      *(bf16x8*)&sB[cur ^ 1][128 + arow][achk] = rb2;
      *(bf16x8*)&sB[cur ^ 1][192 + arow][achk] = rb3;
    }
    __syncthreads();
    cur ^= 1;
  }
  if (APPLY) {
#pragma unroll
    for (int fc = 0; fc < 8; ++fc) {
      const int c = 128 * cg + 16 * fc + (lane & 15);
      const float sc = sC1[c], b2 = sC2[c];
      float* op = out + ((size_t)b * CCH + c) * NPIX + n0 + 32 * rg + ((lane >> 4) << 2);
#pragma unroll
      for (int fr = 0; fr < 2; ++fr) {
        float4 v;
        v.x = acc[fr][fc][0] * sc + b2;
        v.y = acc[fr][fc][1] * sc + b2;
        v.z = acc[fr][fc][2] * sc + b2;
        v.w = acc[fr][fc][3] * sc + b2;
        *(float4*)(op + 16 * fr) = v;
      }
    }
  } else {
    float ps[8], pq[8];
#pragma unroll
    for (int fc = 0; fc < 8; ++fc) {
      const int c = 128 * cg + 16 * fc + (lane & 15);
      const float e = sC1[c];
      float s = 0.f, q = 0.f;
#pragma unroll
      for (int fr = 0; fr < 2; ++fr)
#pragma unroll
        for (int reg = 0; reg < 4; ++reg) {
          const float z = acc[fr][fc][reg] + e;
          s += z; q += z * z;
        }
      s += __shfl_xor(s, 16); s += __shfl_xor(s, 32);
      q += __shfl_xor(q, 16); q += __shfl_xor(q, 32);
      ps[fc] = s; pq[fc] = q;
    }
    if (lane < 16) {
#pragma unroll
      for (int fc = 0; fc < 8; ++fc) {
        redS[w][16 * fc + lane] = ps[fc];
        redQ[w][16 * fc + lane] = pq[fc];
      }
    }
    __syncthreads();
    if (t < 256) {
      const int cg2 = t >> 7, c = t & 127;
      float s = 0.f, q = 0.f;
#pragma unroll
      for (int rg2 = 0; rg2 < 2; ++rg2) {
        s += redS[rg2 * 2 + cg2][c];
        q += redQ[rg2 * 2 + cg2][c];
      }
      // transposed partial layout: [channel][entry]
      ws[OFF_ZPS + (size_t)t * 512 + b * 64 + nblk] = s;
      ws[OFF_ZPQ + (size_t)t * 512 + b * 64 + nblk] = q;
    }
  }
}

// ---------- BN stats -> scale/shift (1 block per channel, contiguous reads) ----------
__global__ __launch_bounds__(64) void k_bnstats(const float* __restrict__ gamma,
                                                const float* __restrict__ beta,
                                                float* __restrict__ ws) {
  const int c = blockIdx.x, t = threadIdx.x;
  const float* PS = ws + OFF_ZPS + (size_t)c * 512;
  const float* PQ = ws + OFF_ZPQ + (size_t)c * 512;
  float s = 0.f, q = 0.f;
#pragma unroll
  for (int e = 0; e < 8; ++e) { s += PS[t + 64 * e]; q += PQ[t + 64 * e]; }
#pragma unroll
  for (int off = 32; off; off >>= 1) { s += __shfl_down(s, off); q += __shfl_down(q, off); }
  if (t == 0) {
    const float mean = s * INVCNT;
    const float var = q * INVCNT - mean * mean;
    const float sc = gamma[c] * rsqrtf(var + 1e-5f);
    ws[OFF_SCALE + c] = sc;
    ws[OFF_SHIFT + c] = beta[c] - mean * sc;
  }
}

extern "C" void kernel_launch(void* const* d_in, const int* in_sizes, int n_in,
                              void* d_out, int out_size, void* d_ws, size_t ws_size,
                              hipStream_t stream) {
  const float* xi  = (const float*)d_in[0];
  const float* xj  = (const float*)d_in[1];
  const float* gw  = (const float*)d_in[2];
  const float* gb  = (const float*)d_in[3];
  const float* thw = (const float*)d_in[4];
  const float* thb = (const float*)d_in[5];
  const float* phw = (const float*)d_in[6];
  const float* phb = (const float*)d_in[7];
  const float* Ww  = (const float*)d_in[8];
  const float* Wb  = (const float*)d_in[9];
  const float* gamma = (const float*)d_in[10];
  const float* beta  = (const float*)d_in[11];
  float* ws = (float*)d_ws;
  float* out = (float*)d_out;

  k_mega<<<dim3(337, 8), 256, 0, stream>>>(xi, xj, Ww, gw, phw, thw, gb, phb, thb, ws);
  k_greduce<<<dim3(192, 8), 256, 0, stream>>>(ws);
  k_kmmat<<<dim3(4, 8), 256, 0, stream>>>(Wb, ws);
  k_zmm<0><<<dim3(64, 8), 256, 0, stream>>>(ws, out);
  k_bnstats<<<256, 64, 0, stream>>>(gamma, beta, ws);
  k_zmm<1><<<dim3(64, 8), 256, 0, stream>>>(ws, out);
}